// Round 14
// baseline (1531.268 us; speedup 1.0000x reference)
//
#include <hip/hip_runtime.h>
#include <hip/hip_bf16.h>
#include <math.h>

#define HIDDEN 2048
#define HEADS 16
#define HEAD_DIM 128
#define LATENT 512
#define SEQ 2048
#define BATCH 2
#define MROWS (BATCH*SEQ)
#define ATTN_SCALE 0.08838834764831845f  // 1/sqrt(128)

typedef unsigned short u16;
typedef __hip_bfloat16 bf16;
typedef __attribute__((ext_vector_type(8))) short bf16x8;
typedef __attribute__((ext_vector_type(4))) float f32x4;

__device__ inline float bf2f(u16 u) { return __uint_as_float(((unsigned)u) << 16); }
__device__ inline short f2bf_s(float v) { bf16 t = __float2bfloat16(v); return *(short*)&t; }

#define GLOAD_LDS(gp, lp) \
    __builtin_amdgcn_global_load_lds((const __attribute__((address_space(1))) unsigned int*)(gp), \
                                     (__attribute__((address_space(3))) unsigned int*)(lp), 16, 0, 0)

// ---------------- mega-prep: rope tables + x cast + all weight transpose-casts ----------------
__global__ __launch_bounds__(256) void prep_kernel(
    const float* __restrict__ x, bf16* __restrict__ xb,
    const float* __restrict__ W_kv_d, const float* __restrict__ W_q_d, const float* __restrict__ W_rk,
    const float* __restrict__ W_k_u, const float* __restrict__ W_v_u,
    const float* __restrict__ W_q_u, const float* __restrict__ W_rq, const float* __restrict__ W_o,
    bf16* __restrict__ Wt_g1, bf16* __restrict__ Wt_g2, bf16* __restrict__ Wt_o,
    float* __restrict__ cosT, float* __restrict__ sinT)
{
    const int tid = threadIdx.x;
    int r = blockIdx.x;

    if (r < 256) {   // rope tables
        int gid = r * 256 + tid;
        int t = gid >> 5, j = gid & 31;
        float inv = powf(10000.0f, -(float)j * (1.0f / 32.0f));
        float ang = (float)t * inv;
        cosT[gid] = cosf(ang);
        sinT[gid] = sinf(ang);
        return;
    }
    r -= 256;
    if (r < 4096) {  // castx
        size_t gid = (size_t)r * 256 + tid;
        const float* p = x + gid * 8;
        float4 a = *(const float4*)p;
        float4 b = *(const float4*)(p + 4);
        bf16 o[8] = {__float2bfloat16(a.x), __float2bfloat16(a.y), __float2bfloat16(a.z), __float2bfloat16(a.w),
                     __float2bfloat16(b.x), __float2bfloat16(b.y), __float2bfloat16(b.z), __float2bfloat16(b.w)};
        *(uint4*)(xb + gid * 8) = *(uint4*)o;
        return;
    }
    r -= 4096;

    // tcast segment select: W (K,N) fp32 -> Wt (N,K) bf16
    const float* W; bf16* Wt; int K, N;
    if (r < 1024)            { W = W_kv_d; Wt = Wt_g1;                        K = 2048; N = 512;  }
    else if (r < 2048)       { r -= 1024; W = W_q_d; Wt = Wt_g1 + (size_t)512 * 2048;  K = 2048; N = 512;  }
    else if (r < 4096)       { r -= 2048; W = W_rk;  Wt = Wt_g1 + (size_t)1024 * 2048; K = 2048; N = 1024; }
    else if (r < 4608)       { r -= 4096; W = W_k_u; Wt = Wt_g2;                       K = 512;  N = 1024; }
    else if (r < 5632)       { r -= 4608; W = W_v_u; Wt = Wt_g2 + (size_t)1024 * 512;  K = 512;  N = 2048; }
    else if (r < 6144)       { r -= 5632; W = W_q_u; Wt = Wt_g2 + (size_t)3072 * 512;  K = 512;  N = 1024; }
    else if (r < 6656)       { r -= 6144; W = W_rq;  Wt = Wt_g2 + (size_t)4096 * 512;  K = 512;  N = 1024; }
    else                     { r -= 6656; W = W_o;   Wt = Wt_o;                        K = 2048; N = 2048; }

    const int kb = r % (K / 32), nb = r / (K / 32);
    const int k0 = kb * 32, n0 = nb * 32;
    __shared__ float T[32][33];
    const int tx = tid & 31, ty = tid >> 5;
#pragma unroll
    for (int p = 0; p < 4; p++) {
        int kr = p * 8 + ty;
        T[kr][tx] = W[(size_t)(k0 + kr) * N + n0 + tx];
    }
    __syncthreads();
#pragma unroll
    for (int p = 0; p < 4; p++) {
        int nr = p * 8 + ty;
        Wt[(size_t)(n0 + nr) * K + k0 + tx] = __float2bfloat16(T[tx][nr]);
    }
}

// ---------------- fused MFMA GEMM ----------------
// FUSE 1:  [0,512) plain->d0(kv_d); [512,1024) plain->d1(q_d); [1024,2048) rope-scatter->d2(kg hi)
// FUSE 23: N=5120, K=512. A = (bn<3072 ? A : A2).
//          [0,1024) k1->d0(kg lo); [1024,3072) v-transpose->d1(vtg);
//          [3072,4096) q1*SCALE->d2(qg lo); [4096,5120) rope(q2)*SCALE->d2(qg hi)
// FUSE 4:  fp32 plain->d0
template<int FUSE>
__global__ __launch_bounds__(256) void mfma_gemm(
    const bf16* __restrict__ A, const bf16* __restrict__ A2, const bf16* __restrict__ Bt,
    const float* __restrict__ bias0, const float* __restrict__ bias1,
    const float* __restrict__ bias2, const float* __restrict__ bias3,
    void* __restrict__ d0, void* __restrict__ d1, void* __restrict__ d2,
    const float* __restrict__ cosT, const float* __restrict__ sinT,
    int M, int N, int K)
{
    constexpr int BM = 128, BN = 128, BK = 32;
    __shared__ __align__(16) short As[2][BM * BK];
    __shared__ __align__(16) short Bs[2][BN * BK];

    const int tid = threadIdx.x;
    const int wid = tid >> 6;
    const int lane = tid & 63;
    const int wm = (wid >> 1) * 64;
    const int wn = (wid & 1) * 64;
    const int bm = blockIdx.y * BM, bn = blockIdx.x * BN;
    const int fr = lane & 15;
    const int fk = lane >> 4;

    const int srowA = wid * 32 + (lane >> 2);
    const int scol = (lane & 3) * 8;

    const bf16* Abase = A;
    if constexpr (FUSE == 23) { if (bn >= 3072) Abase = A2; }

    f32x4 acc[4][4];
#pragma unroll
    for (int mi = 0; mi < 4; mi++)
#pragma unroll
        for (int ni = 0; ni < 4; ni++)
            acc[mi][ni] = (f32x4){0.f, 0.f, 0.f, 0.f};

    const int NT = K / BK;
#pragma unroll
    for (int i = 0; i < 2; i++) {
        GLOAD_LDS(Abase + (size_t)(bm + srowA + i * 16) * K + scol, &As[0][(wid * 32 + i * 16) * BK]);
        GLOAD_LDS(Bt + (size_t)(bn + srowA + i * 16) * K + scol, &Bs[0][(wid * 32 + i * 16) * BK]);
    }

    int cur = 0;
    for (int t = 0; t < NT; t++) {
        __syncthreads();
        if (t + 1 < NT) {
            size_t kk = (size_t)(t + 1) * BK;
#pragma unroll
            for (int i = 0; i < 2; i++) {
                GLOAD_LDS(Abase + (size_t)(bm + srowA + i * 16) * K + kk + scol, &As[cur ^ 1][(wid * 32 + i * 16) * BK]);
                GLOAD_LDS(Bt + (size_t)(bn + srowA + i * 16) * K + kk + scol, &Bs[cur ^ 1][(wid * 32 + i * 16) * BK]);
            }
        }
        bf16x8 af[4], bfr[4];
#pragma unroll
        for (int mi = 0; mi < 4; mi++)
            af[mi] = *(const bf16x8*)&As[cur][(wm + mi * 16 + fr) * BK + fk * 8];
#pragma unroll
        for (int ni = 0; ni < 4; ni++)
            bfr[ni] = *(const bf16x8*)&Bs[cur][(wn + ni * 16 + fr) * BK + fk * 8];
#pragma unroll
        for (int mi = 0; mi < 4; mi++)
#pragma unroll
            for (int ni = 0; ni < 4; ni++)
                acc[mi][ni] = __builtin_amdgcn_mfma_f32_16x16x32_bf16(af[mi], bfr[ni], acc[mi][ni], 0, 0, 0);
        cur ^= 1;
    }

    const int cr = (lane >> 4) * 4;
#pragma unroll
    for (int mi = 0; mi < 4; mi++) {
#pragma unroll
        for (int j = 0; j < 4; j++) {
            int m = bm + wm + mi * 16 + cr + j;
            int bb = m >> 11;
            int s = m & 2047;

            if constexpr (FUSE == 4) {
#pragma unroll
                for (int ni = 0; ni < 4; ni++) {
                    int n = bn + wn + ni * 16 + fr;
                    ((float*)d0)[(size_t)m * N + n] = acc[mi][ni][j] + bias0[n];
                }
            } else if constexpr (FUSE == 1) {
                if (bn < 512) {
#pragma unroll
                    for (int ni = 0; ni < 4; ni++) {
                        int n = bn + wn + ni * 16 + fr;
                        ((bf16*)d0)[(size_t)m * 512 + n] = __float2bfloat16(acc[mi][ni][j] + bias0[n]);
                    }
                } else if (bn < 1024) {
#pragma unroll
                    for (int ni = 0; ni < 4; ni++) {
                        int n = bn + wn + ni * 16 + fr - 512;
                        ((bf16*)d1)[(size_t)m * 512 + n] = __float2bfloat16(acc[mi][ni][j] + bias1[n]);
                    }
                } else {
#pragma unroll
                    for (int ni = 0; ni < 2; ni++) {
                        int nl = bn + wn + ni * 16 + fr - 1024;
                        int hh = nl >> 6, dd = nl & 63;
                        float rot = acc[mi][ni][j] + bias2[nl];
                        float pas = acc[mi][ni + 2][j] + bias2[nl + 32];
                        float c = cosT[s * 32 + dd], sn = sinT[s * 32 + dd];
                        bf16* o = (bf16*)d2 + ((size_t)(bb * HEADS + hh) * SEQ + s) * HEAD_DIM + 64 + dd;
                        o[0]  = __float2bfloat16(rot * c - pas * sn);
                        o[32] = __float2bfloat16(rot * sn + pas * c);
                    }
                }
            } else {   // FUSE == 23
                if (bn < 1024) {
#pragma unroll
                    for (int ni = 0; ni < 4; ni++) {
                        int nl = bn + wn + ni * 16 + fr;
                        int hh = nl >> 6, dd = nl & 63;
                        ((bf16*)d0)[((size_t)(bb * HEADS + hh) * SEQ + s) * HEAD_DIM + dd] =
                            __float2bfloat16(acc[mi][ni][j] + bias0[nl]);
                    }
                } else if (bn < 3072) {
#pragma unroll
                    for (int ni = 0; ni < 4; ni++) {
                        int nl = bn + wn + ni * 16 + fr - 1024;
                        int hh = nl >> 7, dd = nl & 127;
                        ((bf16*)d1)[((size_t)(bb * HEADS + hh) * HEAD_DIM + dd) * SEQ + s] =
                            __float2bfloat16(acc[mi][ni][j] + bias1[nl]);
                    }
                } else if (bn < 4096) {
#pragma unroll
                    for (int ni = 0; ni < 4; ni++) {
                        int nl = bn + wn + ni * 16 + fr - 3072;
                        int hh = nl >> 6, dd = nl & 63;
                        ((bf16*)d2)[((size_t)(bb * HEADS + hh) * SEQ + s) * HEAD_DIM + dd] =
                            __float2bfloat16((acc[mi][ni][j] + bias2[nl]) * ATTN_SCALE);
                    }
                } else {
#pragma unroll
                    for (int ni = 0; ni < 2; ni++) {
                        int nl = bn + wn + ni * 16 + fr - 4096;
                        int hh = nl >> 6, dd = nl & 63;
                        float rot = (acc[mi][ni][j] + bias3[nl]) * ATTN_SCALE;
                        float pas = (acc[mi][ni + 2][j] + bias3[nl + 32]) * ATTN_SCALE;
                        float c = cosT[s * 32 + dd], sn = sinT[s * 32 + dd];
                        bf16* o = (bf16*)d2 + ((size_t)(bb * HEADS + hh) * SEQ + s) * HEAD_DIM + 64 + dd;
                        o[0]  = __float2bfloat16(rot * c - pas * sn);
                        o[32] = __float2bfloat16(rot * sn + pas * c);
                    }
                }
            }
        }
    }
}

// ---------------- MFMA causal flash attention — MERGED paired q-tiles ----------------
// Block processes q-tiles qt1=pid and qt2=31-pid in ONE kt loop sharing each staged
// K/V tile: kf/vf fragments read once feed both q-tiles' MFMAs (kt<=qt1 region).
// P kept in registers (shfl redistribution) — no Ps LDS, no mid-tile LDS round trip.
// Async dbuf K/V staging via global_load_lds, source-swizzled. One barrier per tile.
// 512 blocks: xcd=f&7, slot=f>>3; g=xcd*4+(slot>>4); pid=slot&15.
__global__ __launch_bounds__(256, 2) void attn_mfma_kernel(
    const bf16* __restrict__ qg, const bf16* __restrict__ kg,
    const bf16* __restrict__ vtg, bf16* __restrict__ outp)
{
    const int f = blockIdx.x;
    const int xcd = f & 7, slot = f >> 3;
    const int g = xcd * 4 + (slot >> 4);
    const int pid = slot & 15;
    const int b = g >> 4, h = g & 15;

    const int tid = threadIdx.x;
    const int w = tid >> 6, lane = tid & 63;
    const int fr = lane & 15, fq = lane >> 4;
    const int r7 = fr & 7;

    const bf16* Q  = qg  + (size_t)(b * HEADS + h) * SEQ * HEAD_DIM;
    const bf16* K  = kg  + (size_t)(b * HEADS + h) * SEQ * HEAD_DIM;
    const bf16* Vt = vtg + (size_t)(b * HEADS + h) * HEAD_DIM * SEQ;

    __shared__ __align__(16) short Ks[2][64 * 128];   // 32 KB
    __shared__ __align__(16) short Vs[2][128 * 64];   // 32 KB  -> 64 KB total

    const int krow = tid >> 4;          // +16 per p
    const int kch  = tid & 15;
    const int vrow = tid >> 3;          // +32 per p
    const int vch  = tid & 7;

    const int qt1 = pid, qt2 = 31 - pid;      // qt1 < qt2 always (pid<=15)
    const int q0a = qt1 * 64, q0b = qt2 * 64;
    const int qrow_a = q0a + w * 16 + fr;
    const int qrow_b = q0b + w * 16 + fr;

    bf16x8 qfa[4], qfb[4];
#pragma unroll
    for (int kk = 0; kk < 4; kk++) {
        qfa[kk] = *(const bf16x8*)(Q + (size_t)(q0a + w * 16 + fr) * HEAD_DIM + kk * 32 + fq * 8);
        qfb[kk] = *(const bf16x8*)(Q + (size_t)(q0b + w * 16 + fr) * HEAD_DIM + kk * 32 + fq * 8);
    }

    f32x4 accOa[8], accOb[8];
#pragma unroll
    for (int ci = 0; ci < 8; ci++) {
        accOa[ci] = (f32x4){0.f, 0.f, 0.f, 0.f};
        accOb[ci] = (f32x4){0.f, 0.f, 0.f, 0.f};
    }
    float m_a = -INFINITY, l_a = 0.f, m_b = -INFINITY, l_b = 0.f;

    // prologue: stage tile 0 -> buf 0 (async)
#pragma unroll
    for (int p = 0; p < 4; p++) {
        int rK = krow + p * 16;
        GLOAD_LDS(K + (size_t)rK * HEAD_DIM + ((kch ^ (rK & 7)) * 8), &Ks[0][rK * 128 + kch * 8]);
        int rV = vrow + p * 32;
        GLOAD_LDS(Vt + (size_t)rV * SEQ + ((vch ^ (rV & 7)) * 8), &Vs[0][rV * 64 + vch * 8]);
    }

    // softmax + P-pack for one q-tile: mask/scale done (Q pre-scaled), updates m/l, rescales accO
    auto softmax_pack = [&](f32x4* accS, float& m_run, float& l_run, f32x4* accO,
                            int qrow, int qt_loc, int kt, int* pk) {
        const bool diag = (kt == qt_loc);
        float pv[16];
        float mloc = -INFINITY;
#pragma unroll
        for (int ni = 0; ni < 4; ni++)
#pragma unroll
            for (int reg = 0; reg < 4; reg++) {
                float sc = accS[ni][reg];
                int key = kt * 64 + ni * 16 + fq * 4 + reg;
                if (diag && key > qrow) sc = -INFINITY;
                pv[ni * 4 + reg] = sc;
                mloc = fmaxf(mloc, sc);
            }
        mloc = fmaxf(mloc, __shfl_xor(mloc, 16));
        mloc = fmaxf(mloc, __shfl_xor(mloc, 32));
        float mn = fmaxf(m_run, mloc);
        float rs = __expf(m_run - mn);
        m_run = mn;
        float sum = 0.f;
#pragma unroll
        for (int i = 0; i < 16; i++) {
            float p = __expf(pv[i] - mn);
            pv[i] = p;
            sum += p;
        }
        sum += __shfl_xor(sum, 16);
        sum += __shfl_xor(sum, 32);
        l_run = l_run * rs + sum;
        if (__any(rs < 1.0f)) {
            float rsb[4];
#pragma unroll
            for (int reg = 0; reg < 4; reg++) rsb[reg] = __shfl(rs, fq * 4 + reg);
#pragma unroll
            for (int ci = 0; ci < 8; ci++)
#pragma unroll
                for (int reg = 0; reg < 4; reg++)
                    accO[ci][reg] *= rsb[reg];
        }
        // pack P -> 8 dwords: pk[ni*2+half] = bf16(pv[ni*4+half*2]) | bf16(pv[ni*4+half*2+1])<<16
#pragma unroll
        for (int ni = 0; ni < 4; ni++) {
            pk[ni * 2 + 0] = (int)((unsigned)(u16)f2bf_s(pv[ni * 4 + 0]) | ((unsigned)(u16)f2bf_s(pv[ni * 4 + 1]) << 16));
            pk[ni * 2 + 1] = (int)((unsigned)(u16)f2bf_s(pv[ni * 4 + 2]) | ((unsigned)(u16)f2bf_s(pv[ni * 4 + 3]) << 16));
        }
    };

    // build PV A-fragment for kk from packed pk via lane shuffles:
    // dest dword j <- src lane ((fq&1)*2+(j>>1))*16+fr, src dword (kk*2+(fq>>1))*2+(j&1)
    auto pv_frag = [&](const int* pk, int kk) -> bf16x8 {
        unsigned d[4];
#pragma unroll
        for (int j = 0; j < 4; j++) {
            int srcl = ((fq & 1) * 2 + (j >> 1)) * 16 + fr;
            int r0 = __shfl(pk[(kk * 2 + 0) * 2 + (j & 1)], srcl);
            int r1 = __shfl(pk[(kk * 2 + 1) * 2 + (j & 1)], srcl);
            d[j] = (fq & 2) ? (unsigned)r1 : (unsigned)r0;
        }
        uint4 t = make_uint4(d[0], d[1], d[2], d[3]);
        return *(bf16x8*)&t;
    };

    int cur = 0;
    for (int kt = 0; kt <= qt2; kt++) {
        __syncthreads();   // buf[cur] staged; prior reads of buf[cur^1] done
        if (kt < qt2) {    // async prefetch next tile
#pragma unroll
            for (int p = 0; p < 4; p++) {
                int rK = krow + p * 16;
                GLOAD_LDS(K + (size_t)((kt + 1) * 64 + rK) * HEAD_DIM + ((kch ^ (rK & 7)) * 8),
                          &Ks[cur ^ 1][rK * 128 + kch * 8]);
                int rV = vrow + p * 32;
                GLOAD_LDS(Vt + (size_t)rV * SEQ + (kt + 1) * 64 + ((vch ^ (rV & 7)) * 8),
                          &Vs[cur ^ 1][rV * 64 + vch * 8]);
            }
        }
        const bool doA = (kt <= qt1);

        // QK^T swapped, shared kf: A=K(rows=key), B=Q(rows=q)
        f32x4 accSa[4], accSb[4];
#pragma unroll
        for (int ni = 0; ni < 4; ni++) {
            accSa[ni] = (f32x4){0.f, 0.f, 0.f, 0.f};
            accSb[ni] = (f32x4){0.f, 0.f, 0.f, 0.f};
        }
#pragma unroll
        for (int kk = 0; kk < 4; kk++) {
#pragma unroll
            for (int ni = 0; ni < 4; ni++) {
                bf16x8 kf = *(const bf16x8*)&Ks[cur][(ni * 16 + fr) * 128 + (((kk * 4 + fq) ^ r7) * 8)];
                accSb[ni] = __builtin_amdgcn_mfma_f32_16x16x32_bf16(kf, qfb[kk], accSb[ni], 0, 0, 0);
                if (doA)
                    accSa[ni] = __builtin_amdgcn_mfma_f32_16x16x32_bf16(kf, qfa[kk], accSa[ni], 0, 0, 0);
            }
        }

        int pk_a[8], pk_b[8];
        softmax_pack(accSb, m_b, l_b, accOb, qrow_b, qt2, kt, pk_b);
        if (doA) softmax_pack(accSa, m_a, l_a, accOa, qrow_a, qt1, kt, pk_a);

        // PV shared vf: A=P(rows=q, in-reg), B=Vs(rows=d)
#pragma unroll
        for (int kk = 0; kk < 2; kk++) {
            bf16x8 pfb = pv_frag(pk_b, kk);
            bf16x8 pfa;
            if (doA) pfa = pv_frag(pk_a, kk);
#pragma unroll
            for (int ci = 0; ci < 8; ci++) {
                bf16x8 vf = *(const bf16x8*)&Vs[cur][(ci * 16 + fr) * 64 + (((kk * 4 + fq) ^ r7) * 8)];
                accOb[ci] = __builtin_amdgcn_mfma_f32_16x16x32_bf16(pfb, vf, accOb[ci], 0, 0, 0);
                if (doA)
                    accOa[ci] = __builtin_amdgcn_mfma_f32_16x16x32_bf16(pfa, vf, accOa[ci], 0, 0, 0);
            }
        }
        cur ^= 1;
    }

    // epilogue: both q-tiles
    {
        float linv = 1.0f / l_a;
#pragma unroll
        for (int reg = 0; reg < 4; reg++) {
            float invb = __shfl(linv, fq * 4 + reg);
            bf16* dst = outp + ((size_t)(b * SEQ) + q0a + w * 16 + fq * 4 + reg) * HIDDEN + h * HEAD_DIM + fr;
#pragma unroll
            for (int ci = 0; ci < 8; ci++)
                dst[ci * 16] = __float2bfloat16(accOa[ci][reg] * invb);
        }
    }
    {
        float linv = 1.0f / l_b;
#pragma unroll
        for (int reg = 0; reg < 4; reg++) {
            float invb = __shfl(linv, fq * 4 + reg);
            bf16* dst = outp + ((size_t)(b * SEQ) + q0b + w * 16 + fq * 4 + reg) * HIDDEN + h * HEAD_DIM + fr;
#pragma unroll
            for (int ci = 0; ci < 8; ci++)
                dst[ci * 16] = __float2bfloat16(accOb[ci][reg] * invb);
        }
    }
}

extern "C" void kernel_launch(void* const* d_in, const int* in_sizes, int n_in,
                              void* d_out, int out_size, void* d_ws, size_t ws_size,
                              hipStream_t stream)
{
    const float* x      = (const float*)d_in[0];
    // d_in[1] = attention_mask (int32 causal tril) — causality implemented directly
    const float* W_kv_d = (const float*)d_in[2];
    const float* b_kv_d = (const float*)d_in[3];
    const float* W_q_d  = (const float*)d_in[4];
    const float* b_q_d  = (const float*)d_in[5];
    const float* W_k_u  = (const float*)d_in[6];
    const float* b_k_u  = (const float*)d_in[7];
    const float* W_q_u  = (const float*)d_in[8];
    const float* b_q_u  = (const float*)d_in[9];
    const float* W_v_u  = (const float*)d_in[10];
    const float* b_v_u  = (const float*)d_in[11];
    const float* W_rk   = (const float*)d_in[12];
    const float* b_rk   = (const float*)d_in[13];
    const float* W_rq   = (const float*)d_in[14];
    const float* b_rq   = (const float*)d_in[15];
    const float* W_o    = (const float*)d_in[16];
    const float* b_o    = (const float*)d_in[17];

    // ---- workspace layout (~112 MB) ----
    float* cosT = (float*)d_ws;
    float* sinT = cosT + SEQ * 32;
    bf16* kv_d  = (bf16*)(sinT + SEQ * 32);
    bf16* q_d   = kv_d + (size_t)MROWS * LATENT;
    bf16* qg    = q_d + (size_t)MROWS * LATENT;
    bf16* kg    = qg + (size_t)BATCH * HEADS * SEQ * HEAD_DIM;
    bf16* vtg   = kg + (size_t)BATCH * HEADS * SEQ * HEAD_DIM;
    bf16* attnb = vtg + (size_t)BATCH * HEADS * SEQ * HEAD_DIM;
    bf16* xb    = attnb + (size_t)MROWS * HIDDEN;
    bf16* Wt_g1 = xb + (size_t)MROWS * HIDDEN;
    bf16* Wt_g2 = Wt_g1 + (size_t)2048 * HIDDEN;
    bf16* Wt_o  = Wt_g2 + (size_t)5120 * LATENT;

    prep_kernel<<<15104, 256, 0, stream>>>(
        x, xb, W_kv_d, W_q_d, W_rk, W_k_u, W_v_u, W_q_u, W_rq, W_o,
        Wt_g1, Wt_g2, Wt_o, cosT, sinT);

    mfma_gemm<1><<<dim3(2048 / 128, MROWS / 128), 256, 0, stream>>>(
        xb, nullptr, Wt_g1, b_kv_d, b_q_d, b_rk, nullptr, kv_d, q_d, kg, cosT, sinT, MROWS, 2048, HIDDEN);

    mfma_gemm<23><<<dim3(5120 / 128, MROWS / 128), 256, 0, stream>>>(
        kv_d, q_d, Wt_g2, b_k_u, b_v_u, b_q_u, b_rq, kg, vtg, qg, cosT, sinT, MROWS, 5120, LATENT);

    attn_mfma_kernel<<<512, 256, 0, stream>>>(qg, kg, vtg, attnb);

    mfma_gemm<4><<<dim3(2048 / 128, MROWS / 128), 256, 0, stream>>>(
        attnb, nullptr, Wt_o, b_o, nullptr, nullptr, nullptr, d_out, nullptr, nullptr, nullptr, nullptr, MROWS, 2048, HIDDEN);
}

// Round 15
// 257.596 us; speedup vs baseline: 5.9444x; 5.9444x over previous
//
#include <hip/hip_runtime.h>
#include <hip/hip_bf16.h>
#include <math.h>

#define HIDDEN 2048
#define HEADS 16
#define HEAD_DIM 128
#define LATENT 512
#define SEQ 2048
#define BATCH 2
#define MROWS (BATCH*SEQ)
#define ATTN_SCALE 0.08838834764831845f  // 1/sqrt(128)

typedef unsigned short u16;
typedef __hip_bfloat16 bf16;
typedef __attribute__((ext_vector_type(8))) short bf16x8;
typedef __attribute__((ext_vector_type(4))) float f32x4;

__device__ inline float bf2f(u16 u) { return __uint_as_float(((unsigned)u) << 16); }
__device__ inline short f2bf_s(float v) { bf16 t = __float2bfloat16(v); return *(short*)&t; }

#define GLOAD_LDS(gp, lp) \
    __builtin_amdgcn_global_load_lds((const __attribute__((address_space(1))) unsigned int*)(gp), \
                                     (__attribute__((address_space(3))) unsigned int*)(lp), 16, 0, 0)

// ---------------- mega-prep: rope tables + x cast + all weight transpose-casts ----------------
__global__ __launch_bounds__(256) void prep_kernel(
    const float* __restrict__ x, bf16* __restrict__ xb,
    const float* __restrict__ W_kv_d, const float* __restrict__ W_q_d, const float* __restrict__ W_rk,
    const float* __restrict__ W_k_u, const float* __restrict__ W_v_u,
    const float* __restrict__ W_q_u, const float* __restrict__ W_rq, const float* __restrict__ W_o,
    bf16* __restrict__ Wt_g1, bf16* __restrict__ Wt_g2, bf16* __restrict__ Wt_o,
    float* __restrict__ cosT, float* __restrict__ sinT)
{
    const int tid = threadIdx.x;
    int r = blockIdx.x;

    if (r < 256) {   // rope tables
        int gid = r * 256 + tid;
        int t = gid >> 5, j = gid & 31;
        float inv = powf(10000.0f, -(float)j * (1.0f / 32.0f));
        float ang = (float)t * inv;
        cosT[gid] = cosf(ang);
        sinT[gid] = sinf(ang);
        return;
    }
    r -= 256;
    if (r < 4096) {  // castx
        size_t gid = (size_t)r * 256 + tid;
        const float* p = x + gid * 8;
        float4 a = *(const float4*)p;
        float4 b = *(const float4*)(p + 4);
        bf16 o[8] = {__float2bfloat16(a.x), __float2bfloat16(a.y), __float2bfloat16(a.z), __float2bfloat16(a.w),
                     __float2bfloat16(b.x), __float2bfloat16(b.y), __float2bfloat16(b.z), __float2bfloat16(b.w)};
        *(uint4*)(xb + gid * 8) = *(uint4*)o;
        return;
    }
    r -= 4096;

    // tcast segment select: W (K,N) fp32 -> Wt (N,K) bf16
    const float* W; bf16* Wt; int K, N;
    if (r < 1024)            { W = W_kv_d; Wt = Wt_g1;                        K = 2048; N = 512;  }
    else if (r < 2048)       { r -= 1024; W = W_q_d; Wt = Wt_g1 + (size_t)512 * 2048;  K = 2048; N = 512;  }
    else if (r < 4096)       { r -= 2048; W = W_rk;  Wt = Wt_g1 + (size_t)1024 * 2048; K = 2048; N = 1024; }
    else if (r < 4608)       { r -= 4096; W = W_k_u; Wt = Wt_g2;                       K = 512;  N = 1024; }
    else if (r < 5632)       { r -= 4608; W = W_v_u; Wt = Wt_g2 + (size_t)1024 * 512;  K = 512;  N = 2048; }
    else if (r < 6144)       { r -= 5632; W = W_q_u; Wt = Wt_g2 + (size_t)3072 * 512;  K = 512;  N = 1024; }
    else if (r < 6656)       { r -= 6144; W = W_rq;  Wt = Wt_g2 + (size_t)4096 * 512;  K = 512;  N = 1024; }
    else                     { r -= 6656; W = W_o;   Wt = Wt_o;                        K = 2048; N = 2048; }

    const int kb = r % (K / 32), nb = r / (K / 32);
    const int k0 = kb * 32, n0 = nb * 32;
    __shared__ float T[32][33];
    const int tx = tid & 31, ty = tid >> 5;
#pragma unroll
    for (int p = 0; p < 4; p++) {
        int kr = p * 8 + ty;
        T[kr][tx] = W[(size_t)(k0 + kr) * N + n0 + tx];
    }
    __syncthreads();
#pragma unroll
    for (int p = 0; p < 4; p++) {
        int nr = p * 8 + ty;
        Wt[(size_t)(n0 + nr) * K + k0 + tx] = __float2bfloat16(T[tx][nr]);
    }
}

// ---------------- fused MFMA GEMM ----------------
// FUSE 1:  [0,512) plain->d0(kv_d); [512,1024) plain->d1(q_d); [1024,2048) rope-scatter->d2(kg hi)
// FUSE 23: N=5120, K=512. A = (bn<3072 ? A : A2).
//          [0,1024) k1->d0(kg lo); [1024,3072) v-transpose->d1(vtg);
//          [3072,4096) q1*SCALE->d2(qg lo); [4096,5120) rope(q2)*SCALE->d2(qg hi)
// FUSE 4:  fp32 plain->d0
template<int FUSE>
__global__ __launch_bounds__(256) void mfma_gemm(
    const bf16* __restrict__ A, const bf16* __restrict__ A2, const bf16* __restrict__ Bt,
    const float* __restrict__ bias0, const float* __restrict__ bias1,
    const float* __restrict__ bias2, const float* __restrict__ bias3,
    void* __restrict__ d0, void* __restrict__ d1, void* __restrict__ d2,
    const float* __restrict__ cosT, const float* __restrict__ sinT,
    int M, int N, int K)
{
    constexpr int BM = 128, BN = 128, BK = 32;
    __shared__ __align__(16) short As[2][BM * BK];
    __shared__ __align__(16) short Bs[2][BN * BK];

    const int tid = threadIdx.x;
    const int wid = tid >> 6;
    const int lane = tid & 63;
    const int wm = (wid >> 1) * 64;
    const int wn = (wid & 1) * 64;
    const int bm = blockIdx.y * BM, bn = blockIdx.x * BN;
    const int fr = lane & 15;
    const int fk = lane >> 4;

    const int srowA = wid * 32 + (lane >> 2);
    const int scol = (lane & 3) * 8;

    const bf16* Abase = A;
    if constexpr (FUSE == 23) { if (bn >= 3072) Abase = A2; }

    f32x4 acc[4][4];
#pragma unroll
    for (int mi = 0; mi < 4; mi++)
#pragma unroll
        for (int ni = 0; ni < 4; ni++)
            acc[mi][ni] = (f32x4){0.f, 0.f, 0.f, 0.f};

    const int NT = K / BK;
#pragma unroll
    for (int i = 0; i < 2; i++) {
        GLOAD_LDS(Abase + (size_t)(bm + srowA + i * 16) * K + scol, &As[0][(wid * 32 + i * 16) * BK]);
        GLOAD_LDS(Bt + (size_t)(bn + srowA + i * 16) * K + scol, &Bs[0][(wid * 32 + i * 16) * BK]);
    }

    int cur = 0;
    for (int t = 0; t < NT; t++) {
        __syncthreads();
        if (t + 1 < NT) {
            size_t kk = (size_t)(t + 1) * BK;
#pragma unroll
            for (int i = 0; i < 2; i++) {
                GLOAD_LDS(Abase + (size_t)(bm + srowA + i * 16) * K + kk + scol, &As[cur ^ 1][(wid * 32 + i * 16) * BK]);
                GLOAD_LDS(Bt + (size_t)(bn + srowA + i * 16) * K + kk + scol, &Bs[cur ^ 1][(wid * 32 + i * 16) * BK]);
            }
        }
        bf16x8 af[4], bfr[4];
#pragma unroll
        for (int mi = 0; mi < 4; mi++)
            af[mi] = *(const bf16x8*)&As[cur][(wm + mi * 16 + fr) * BK + fk * 8];
#pragma unroll
        for (int ni = 0; ni < 4; ni++)
            bfr[ni] = *(const bf16x8*)&Bs[cur][(wn + ni * 16 + fr) * BK + fk * 8];
#pragma unroll
        for (int mi = 0; mi < 4; mi++)
#pragma unroll
            for (int ni = 0; ni < 4; ni++)
                acc[mi][ni] = __builtin_amdgcn_mfma_f32_16x16x32_bf16(af[mi], bfr[ni], acc[mi][ni], 0, 0, 0);
        cur ^= 1;
    }

    const int cr = (lane >> 4) * 4;
#pragma unroll
    for (int mi = 0; mi < 4; mi++) {
#pragma unroll
        for (int j = 0; j < 4; j++) {
            int m = bm + wm + mi * 16 + cr + j;
            int bb = m >> 11;
            int s = m & 2047;

            if constexpr (FUSE == 4) {
#pragma unroll
                for (int ni = 0; ni < 4; ni++) {
                    int n = bn + wn + ni * 16 + fr;
                    ((float*)d0)[(size_t)m * N + n] = acc[mi][ni][j] + bias0[n];
                }
            } else if constexpr (FUSE == 1) {
                if (bn < 512) {
#pragma unroll
                    for (int ni = 0; ni < 4; ni++) {
                        int n = bn + wn + ni * 16 + fr;
                        ((bf16*)d0)[(size_t)m * 512 + n] = __float2bfloat16(acc[mi][ni][j] + bias0[n]);
                    }
                } else if (bn < 1024) {
#pragma unroll
                    for (int ni = 0; ni < 4; ni++) {
                        int n = bn + wn + ni * 16 + fr - 512;
                        ((bf16*)d1)[(size_t)m * 512 + n] = __float2bfloat16(acc[mi][ni][j] + bias1[n]);
                    }
                } else {
#pragma unroll
                    for (int ni = 0; ni < 2; ni++) {
                        int nl = bn + wn + ni * 16 + fr - 1024;
                        int hh = nl >> 6, dd = nl & 63;
                        float rot = acc[mi][ni][j] + bias2[nl];
                        float pas = acc[mi][ni + 2][j] + bias2[nl + 32];
                        float c = cosT[s * 32 + dd], sn = sinT[s * 32 + dd];
                        bf16* o = (bf16*)d2 + ((size_t)(bb * HEADS + hh) * SEQ + s) * HEAD_DIM + 64 + dd;
                        o[0]  = __float2bfloat16(rot * c - pas * sn);
                        o[32] = __float2bfloat16(rot * sn + pas * c);
                    }
                }
            } else {   // FUSE == 23
                if (bn < 1024) {
#pragma unroll
                    for (int ni = 0; ni < 4; ni++) {
                        int nl = bn + wn + ni * 16 + fr;
                        int hh = nl >> 6, dd = nl & 63;
                        ((bf16*)d0)[((size_t)(bb * HEADS + hh) * SEQ + s) * HEAD_DIM + dd] =
                            __float2bfloat16(acc[mi][ni][j] + bias0[nl]);
                    }
                } else if (bn < 3072) {
#pragma unroll
                    for (int ni = 0; ni < 4; ni++) {
                        int nl = bn + wn + ni * 16 + fr - 1024;
                        int hh = nl >> 7, dd = nl & 127;
                        ((bf16*)d1)[((size_t)(bb * HEADS + hh) * HEAD_DIM + dd) * SEQ + s] =
                            __float2bfloat16(acc[mi][ni][j] + bias1[nl]);
                    }
                } else if (bn < 4096) {
#pragma unroll
                    for (int ni = 0; ni < 4; ni++) {
                        int nl = bn + wn + ni * 16 + fr - 3072;
                        int hh = nl >> 6, dd = nl & 63;
                        ((bf16*)d2)[((size_t)(bb * HEADS + hh) * SEQ + s) * HEAD_DIM + dd] =
                            __float2bfloat16((acc[mi][ni][j] + bias2[nl]) * ATTN_SCALE);
                    }
                } else {
#pragma unroll
                    for (int ni = 0; ni < 2; ni++) {
                        int nl = bn + wn + ni * 16 + fr - 4096;
                        int hh = nl >> 6, dd = nl & 63;
                        float rot = (acc[mi][ni][j] + bias3[nl]) * ATTN_SCALE;
                        float pas = (acc[mi][ni + 2][j] + bias3[nl + 32]) * ATTN_SCALE;
                        float c = cosT[s * 32 + dd], sn = sinT[s * 32 + dd];
                        bf16* o = (bf16*)d2 + ((size_t)(bb * HEADS + hh) * SEQ + s) * HEAD_DIM + 64 + dd;
                        o[0]  = __float2bfloat16(rot * c - pas * sn);
                        o[32] = __float2bfloat16(rot * sn + pas * c);
                    }
                }
            }
        }
    }
}

// ---------------- MFMA causal flash attention (r12 version — best measured: 80.6 µs) ----------------
// Async double-buffered K/V staging via global_load_lds with pre-swizzled SOURCE
// (linear LDS dest; reads apply the same XOR involution). One barrier per tile:
// Ps is intra-wave only (write row w*16+fr, read row w*16+fr) -> no mid barrier.
// q (pre-scaled),k: (B,H,S,128); vt: (B,H,128,S); out: (B,S,H*128) bf16
// 512 blocks: xcd=f&7, slot=f>>3; g=xcd*4+(slot>>4) pins each (b,h) to one XCD; pid=slot&15.
__global__ __launch_bounds__(256) void attn_mfma_kernel(
    const bf16* __restrict__ qg, const bf16* __restrict__ kg,
    const bf16* __restrict__ vtg, bf16* __restrict__ outp)
{
    const int f = blockIdx.x;
    const int xcd = f & 7, slot = f >> 3;
    const int g = xcd * 4 + (slot >> 4);   // 0..31
    const int pid = slot & 15;
    const int b = g >> 4, h = g & 15;

    const int tid = threadIdx.x;
    const int w = tid >> 6, lane = tid & 63;
    const int fr = lane & 15, fq = lane >> 4;
    const int r7 = fr & 7;

    const bf16* Q  = qg  + (size_t)(b * HEADS + h) * SEQ * HEAD_DIM;
    const bf16* K  = kg  + (size_t)(b * HEADS + h) * SEQ * HEAD_DIM;
    const bf16* Vt = vtg + (size_t)(b * HEADS + h) * HEAD_DIM * SEQ;

    __shared__ __align__(16) short Ks[2][64 * 128];   // [key][d]
    __shared__ __align__(16) short Vs[2][128 * 64];   // [d][key]
    __shared__ __align__(16) short Ps[64 * 64];       // [q][key]

    const int krow = tid >> 4;          // +16 per p
    const int kch  = tid & 15;
    const int vrow = tid >> 3;          // +32 per p
    const int vch  = tid & 7;

#pragma unroll 1
    for (int seg = 0; seg < 2; seg++) {
        const int qt = seg ? (31 - pid) : pid;
        const int q0 = qt * 64;
        const int qrow = q0 + w * 16 + fr;

        bf16x8 qf[4];
#pragma unroll
        for (int kk = 0; kk < 4; kk++)
            qf[kk] = *(const bf16x8*)(Q + (size_t)(q0 + w * 16 + fr) * HEAD_DIM + kk * 32 + fq * 8);

        f32x4 accO[8];
#pragma unroll
        for (int ci = 0; ci < 8; ci++) accO[ci] = (f32x4){0.f, 0.f, 0.f, 0.f};
        float m_run = -INFINITY, l_run = 0.f;

        __syncthreads();   // prior segment's reads of all buffers complete
#pragma unroll
        for (int p = 0; p < 4; p++) {
            int rK = krow + p * 16;
            GLOAD_LDS(K + (size_t)rK * HEAD_DIM + ((kch ^ (rK & 7)) * 8), &Ks[0][rK * 128 + kch * 8]);
            int rV = vrow + p * 32;
            GLOAD_LDS(Vt + (size_t)rV * SEQ + ((vch ^ (rV & 7)) * 8), &Vs[0][rV * 64 + vch * 8]);
        }

        int cur = 0;
        for (int kt = 0; kt <= qt; kt++) {
            __syncthreads();   // drains vmcnt: buf[cur] ready; prior reads of buf[cur^1] done
            if (kt < qt) {     // async prefetch of next tile
#pragma unroll
                for (int p = 0; p < 4; p++) {
                    int rK = krow + p * 16;
                    GLOAD_LDS(K + (size_t)((kt + 1) * 64 + rK) * HEAD_DIM + ((kch ^ (rK & 7)) * 8),
                              &Ks[cur ^ 1][rK * 128 + kch * 8]);
                    int rV = vrow + p * 32;
                    GLOAD_LDS(Vt + (size_t)rV * SEQ + (kt + 1) * 64 + ((vch ^ (rV & 7)) * 8),
                              &Vs[cur ^ 1][rV * 64 + vch * 8]);
                }
            }

            // QK^T swapped: A=K(rows=key), B=Q(rows=q). C: col=fr=q, row=fq*4+reg=key_sub
            f32x4 accS[4];
#pragma unroll
            for (int ni = 0; ni < 4; ni++) accS[ni] = (f32x4){0.f, 0.f, 0.f, 0.f};
#pragma unroll
            for (int kk = 0; kk < 4; kk++) {
#pragma unroll
                for (int ni = 0; ni < 4; ni++) {
                    bf16x8 kf = *(const bf16x8*)&Ks[cur][(ni * 16 + fr) * 128 + (((kk * 4 + fq) ^ r7) * 8)];
                    accS[ni] = __builtin_amdgcn_mfma_f32_16x16x32_bf16(kf, qf[kk], accS[ni], 0, 0, 0);
                }
            }

            // lane-local softmax (Q pre-scaled)
            const bool diag = (kt == qt);
            float pv[16];
            float mloc = -INFINITY;
#pragma unroll
            for (int ni = 0; ni < 4; ni++)
#pragma unroll
                for (int reg = 0; reg < 4; reg++) {
                    float sc = accS[ni][reg];
                    int key = kt * 64 + ni * 16 + fq * 4 + reg;
                    if (diag && key > qrow) sc = -INFINITY;
                    pv[ni * 4 + reg] = sc;
                    mloc = fmaxf(mloc, sc);
                }
            mloc = fmaxf(mloc, __shfl_xor(mloc, 16));
            mloc = fmaxf(mloc, __shfl_xor(mloc, 32));
            float mn = fmaxf(m_run, mloc);
            float rs = __expf(m_run - mn);
            m_run = mn;
            float sum = 0.f;
#pragma unroll
            for (int i = 0; i < 16; i++) {
                float p = __expf(pv[i] - mn);
                pv[i] = p;
                sum += p;
            }
            sum += __shfl_xor(sum, 16);
            sum += __shfl_xor(sum, 32);
            l_run = l_run * rs + sum;

            // T13: skip rescale when max unchanged for all rows
            if (__any(rs < 1.0f)) {
                float rsb[4];
#pragma unroll
                for (int reg = 0; reg < 4; reg++) rsb[reg] = __shfl(rs, fq * 4 + reg);
#pragma unroll
                for (int ci = 0; ci < 8; ci++)
#pragma unroll
                    for (int reg = 0; reg < 4; reg++)
                        accO[ci][reg] *= rsb[reg];
            }

            // P write (intra-wave rows; lgkmcnt ordering suffices, no barrier)
#pragma unroll
            for (int ni = 0; ni < 4; ni++) {
                unsigned lo = (unsigned)(u16)f2bf_s(pv[ni * 4 + 0]) | ((unsigned)(u16)f2bf_s(pv[ni * 4 + 1]) << 16);
                unsigned hi = (unsigned)(u16)f2bf_s(pv[ni * 4 + 2]) | ((unsigned)(u16)f2bf_s(pv[ni * 4 + 3]) << 16);
                uint2 u; u.x = lo; u.y = hi;
                *(uint2*)&Ps[(w * 16 + fr) * 64 + (((2 * ni + (fq >> 1)) ^ r7) * 8) + (fq & 1) * 4] = u;
            }

            // PV: A=Ps(rows=q), B=Vs(rows=d). C: col=fr=d_sub, row=fq*4+reg=q_sub
#pragma unroll
            for (int kk = 0; kk < 2; kk++) {
                bf16x8 pf = *(const bf16x8*)&Ps[(w * 16 + fr) * 64 + (((kk * 4 + fq) ^ r7) * 8)];
#pragma unroll
                for (int ci = 0; ci < 8; ci++) {
                    bf16x8 vf = *(const bf16x8*)&Vs[cur][(ci * 16 + fr) * 64 + (((kk * 4 + fq) ^ r7) * 8)];
                    accO[ci] = __builtin_amdgcn_mfma_f32_16x16x32_bf16(pf, vf, accO[ci], 0, 0, 0);
                }
            }
            cur ^= 1;
        }

        // epilogue
        float linv = 1.0f / l_run;
#pragma unroll
        for (int reg = 0; reg < 4; reg++) {
            float invb = __shfl(linv, fq * 4 + reg);
            bf16* dst = outp + ((size_t)(b * SEQ) + q0 + w * 16 + fq * 4 + reg) * HIDDEN + h * HEAD_DIM + fr;
#pragma unroll
            for (int ci = 0; ci < 8; ci++)
                dst[ci * 16] = __float2bfloat16(accO[ci][reg] * invb);
        }
    }
}

extern "C" void kernel_launch(void* const* d_in, const int* in_sizes, int n_in,
                              void* d_out, int out_size, void* d_ws, size_t ws_size,
                              hipStream_t stream)
{
    const float* x      = (const float*)d_in[0];
    // d_in[1] = attention_mask (int32 causal tril) — causality implemented directly
    const float* W_kv_d = (const float*)d_in[2];
    const float* b_kv_d = (const float*)d_in[3];
    const float* W_q_d  = (const float*)d_in[4];
    const float* b_q_d  = (const float*)d_in[5];
    const float* W_k_u  = (const float*)d_in[6];
    const float* b_k_u  = (const float*)d_in[7];
    const float* W_q_u  = (const float*)d_in[8];
    const float* b_q_u  = (const float*)d_in[9];
    const float* W_v_u  = (const float*)d_in[10];
    const float* b_v_u  = (const float*)d_in[11];
    const float* W_rk   = (const float*)d_in[12];
    const float* b_rk   = (const float*)d_in[13];
    const float* W_rq   = (const float*)d_in[14];
    const float* b_rq   = (const float*)d_in[15];
    const float* W_o    = (const float*)d_in[16];
    const float* b_o    = (const float*)d_in[17];

    // ---- workspace layout (~112 MB) ----
    float* cosT = (float*)d_ws;
    float* sinT = cosT + SEQ * 32;
    bf16* kv_d  = (bf16*)(sinT + SEQ * 32);
    bf16* q_d   = kv_d + (size_t)MROWS * LATENT;
    bf16* qg    = q_d + (size_t)MROWS * LATENT;
    bf16* kg    = qg + (size_t)BATCH * HEADS * SEQ * HEAD_DIM;
    bf16* vtg   = kg + (size_t)BATCH * HEADS * SEQ * HEAD_DIM;
    bf16* attnb = vtg + (size_t)BATCH * HEADS * SEQ * HEAD_DIM;
    bf16* xb    = attnb + (size_t)MROWS * HIDDEN;
    bf16* Wt_g1 = xb + (size_t)MROWS * HIDDEN;
    bf16* Wt_g2 = Wt_g1 + (size_t)2048 * HIDDEN;
    bf16* Wt_o  = Wt_g2 + (size_t)5120 * LATENT;

    prep_kernel<<<15104, 256, 0, stream>>>(
        x, xb, W_kv_d, W_q_d, W_rk, W_k_u, W_v_u, W_q_u, W_rq, W_o,
        Wt_g1, Wt_g2, Wt_o, cosT, sinT);

    mfma_gemm<1><<<dim3(2048 / 128, MROWS / 128), 256, 0, stream>>>(
        xb, nullptr, Wt_g1, b_kv_d, b_q_d, b_rk, nullptr, kv_d, q_d, kg, cosT, sinT, MROWS, 2048, HIDDEN);

    mfma_gemm<23><<<dim3(5120 / 128, MROWS / 128), 256, 0, stream>>>(
        kv_d, q_d, Wt_g2, b_k_u, b_v_u, b_q_u, b_rq, kg, vtg, qg, cosT, sinT, MROWS, 5120, LATENT);

    attn_mfma_kernel<<<512, 256, 0, stream>>>(qg, kg, vtg, attnb);

    mfma_gemm<4><<<dim3(2048 / 128, MROWS / 128), 256, 0, stream>>>(
        attnb, nullptr, Wt_o, b_o, nullptr, nullptr, nullptr, d_out, nullptr, nullptr, nullptr, nullptr, MROWS, 2048, HIDDEN);
}

// Round 16
// 241.396 us; speedup vs baseline: 6.3434x; 1.0671x over previous
//
#include <hip/hip_runtime.h>
#include <hip/hip_bf16.h>
#include <math.h>

#define HIDDEN 2048
#define HEADS 16
#define HEAD_DIM 128
#define LATENT 512
#define SEQ 2048
#define BATCH 2
#define MROWS (BATCH*SEQ)
#define ATTN_SCALE 0.08838834764831845f  // 1/sqrt(128)

typedef unsigned short u16;
typedef __hip_bfloat16 bf16;
typedef __attribute__((ext_vector_type(8))) short bf16x8;
typedef __attribute__((ext_vector_type(4))) float f32x4;

__device__ inline float bf2f(u16 u) { return __uint_as_float(((unsigned)u) << 16); }
__device__ inline short f2bf_s(float v) { bf16 t = __float2bfloat16(v); return *(short*)&t; }

#define GLOAD_LDS(gp, lp) \
    __builtin_amdgcn_global_load_lds((const __attribute__((address_space(1))) unsigned int*)(gp), \
                                     (__attribute__((address_space(3))) unsigned int*)(lp), 16, 0, 0)

// ---------------- mega-prep: rope tables + x cast + all weight transpose-casts ----------------
__global__ __launch_bounds__(256) void prep_kernel(
    const float* __restrict__ x, bf16* __restrict__ xb,
    const float* __restrict__ W_kv_d, const float* __restrict__ W_q_d, const float* __restrict__ W_rk,
    const float* __restrict__ W_k_u, const float* __restrict__ W_v_u,
    const float* __restrict__ W_q_u, const float* __restrict__ W_rq, const float* __restrict__ W_o,
    bf16* __restrict__ Wt_g1, bf16* __restrict__ Wt_g2, bf16* __restrict__ Wt_o,
    float* __restrict__ cosT, float* __restrict__ sinT)
{
    const int tid = threadIdx.x;
    int r = blockIdx.x;

    if (r < 256) {   // rope tables
        int gid = r * 256 + tid;
        int t = gid >> 5, j = gid & 31;
        float inv = powf(10000.0f, -(float)j * (1.0f / 32.0f));
        float ang = (float)t * inv;
        cosT[gid] = cosf(ang);
        sinT[gid] = sinf(ang);
        return;
    }
    r -= 256;
    if (r < 4096) {  // castx
        size_t gid = (size_t)r * 256 + tid;
        const float* p = x + gid * 8;
        float4 a = *(const float4*)p;
        float4 b = *(const float4*)(p + 4);
        bf16 o[8] = {__float2bfloat16(a.x), __float2bfloat16(a.y), __float2bfloat16(a.z), __float2bfloat16(a.w),
                     __float2bfloat16(b.x), __float2bfloat16(b.y), __float2bfloat16(b.z), __float2bfloat16(b.w)};
        *(uint4*)(xb + gid * 8) = *(uint4*)o;
        return;
    }
    r -= 4096;

    // tcast segment select: W (K,N) fp32 -> Wt (N,K) bf16
    const float* W; bf16* Wt; int K, N;
    if (r < 1024)            { W = W_kv_d; Wt = Wt_g1;                        K = 2048; N = 512;  }
    else if (r < 2048)       { r -= 1024; W = W_q_d; Wt = Wt_g1 + (size_t)512 * 2048;  K = 2048; N = 512;  }
    else if (r < 4096)       { r -= 2048; W = W_rk;  Wt = Wt_g1 + (size_t)1024 * 2048; K = 2048; N = 1024; }
    else if (r < 4608)       { r -= 4096; W = W_k_u; Wt = Wt_g2;                       K = 512;  N = 1024; }
    else if (r < 5632)       { r -= 4608; W = W_v_u; Wt = Wt_g2 + (size_t)1024 * 512;  K = 512;  N = 2048; }
    else if (r < 6144)       { r -= 5632; W = W_q_u; Wt = Wt_g2 + (size_t)3072 * 512;  K = 512;  N = 1024; }
    else if (r < 6656)       { r -= 6144; W = W_rq;  Wt = Wt_g2 + (size_t)4096 * 512;  K = 512;  N = 1024; }
    else                     { r -= 6656; W = W_o;   Wt = Wt_o;                        K = 2048; N = 2048; }

    const int kb = r % (K / 32), nb = r / (K / 32);
    const int k0 = kb * 32, n0 = nb * 32;
    __shared__ float T[32][33];
    const int tx = tid & 31, ty = tid >> 5;
#pragma unroll
    for (int p = 0; p < 4; p++) {
        int kr = p * 8 + ty;
        T[kr][tx] = W[(size_t)(k0 + kr) * N + n0 + tx];
    }
    __syncthreads();
#pragma unroll
    for (int p = 0; p < 4; p++) {
        int nr = p * 8 + ty;
        Wt[(size_t)(n0 + nr) * K + k0 + tx] = __float2bfloat16(T[tx][nr]);
    }
}

// ---------------- fused MFMA GEMM ----------------
// FUSE 1:  [0,512) plain->d0(kv_d); [512,1024) plain->d1(q_d); [1024,2048) rope-scatter->d2(kg hi)
// FUSE 23: N=5120, K=512. A = (bn<3072 ? A : A2).
//          [0,1024) k1->d0(kg lo); [1024,3072) v-transpose via LDS panels->d1(vtg);
//          [3072,4096) q1*SCALE->d2(qg lo); [4096,5120) rope(q2)*SCALE->d2(qg hi)
// FUSE 4:  fp32 plain->d0
template<int FUSE>
__global__ __launch_bounds__(256) void mfma_gemm(
    const bf16* __restrict__ A, const bf16* __restrict__ A2, const bf16* __restrict__ Bt,
    const float* __restrict__ bias0, const float* __restrict__ bias1,
    const float* __restrict__ bias2, const float* __restrict__ bias3,
    void* __restrict__ d0, void* __restrict__ d1, void* __restrict__ d2,
    const float* __restrict__ cosT, const float* __restrict__ sinT,
    int M, int N, int K)
{
    constexpr int BM = 128, BN = 128, BK = 32;
    __shared__ __align__(16) short As[2][BM * BK];
    __shared__ __align__(16) short Bs[2][BN * BK];

    const int tid = threadIdx.x;
    const int wid = tid >> 6;
    const int lane = tid & 63;
    const int wm = (wid >> 1) * 64;
    const int wn = (wid & 1) * 64;
    const int bm = blockIdx.y * BM, bn = blockIdx.x * BN;
    const int fr = lane & 15;
    const int fk = lane >> 4;

    const int srowA = wid * 32 + (lane >> 2);
    const int scol = (lane & 3) * 8;

    const bf16* Abase = A;
    if constexpr (FUSE == 23) { if (bn >= 3072) Abase = A2; }

    f32x4 acc[4][4];
#pragma unroll
    for (int mi = 0; mi < 4; mi++)
#pragma unroll
        for (int ni = 0; ni < 4; ni++)
            acc[mi][ni] = (f32x4){0.f, 0.f, 0.f, 0.f};

    const int NT = K / BK;
#pragma unroll
    for (int i = 0; i < 2; i++) {
        GLOAD_LDS(Abase + (size_t)(bm + srowA + i * 16) * K + scol, &As[0][(wid * 32 + i * 16) * BK]);
        GLOAD_LDS(Bt + (size_t)(bn + srowA + i * 16) * K + scol, &Bs[0][(wid * 32 + i * 16) * BK]);
    }

    int cur = 0;
    for (int t = 0; t < NT; t++) {
        __syncthreads();
        if (t + 1 < NT) {
            size_t kk = (size_t)(t + 1) * BK;
#pragma unroll
            for (int i = 0; i < 2; i++) {
                GLOAD_LDS(Abase + (size_t)(bm + srowA + i * 16) * K + kk + scol, &As[cur ^ 1][(wid * 32 + i * 16) * BK]);
                GLOAD_LDS(Bt + (size_t)(bn + srowA + i * 16) * K + kk + scol, &Bs[cur ^ 1][(wid * 32 + i * 16) * BK]);
            }
        }
        bf16x8 af[4], bfr[4];
#pragma unroll
        for (int mi = 0; mi < 4; mi++)
            af[mi] = *(const bf16x8*)&As[cur][(wm + mi * 16 + fr) * BK + fk * 8];
#pragma unroll
        for (int ni = 0; ni < 4; ni++)
            bfr[ni] = *(const bf16x8*)&Bs[cur][(wn + ni * 16 + fr) * BK + fk * 8];
#pragma unroll
        for (int mi = 0; mi < 4; mi++)
#pragma unroll
            for (int ni = 0; ni < 4; ni++)
                acc[mi][ni] = __builtin_amdgcn_mfma_f32_16x16x32_bf16(af[mi], bfr[ni], acc[mi][ni], 0, 0, 0);
        cur ^= 1;
    }

    const int cr = (lane >> 4) * 4;

    if constexpr (FUSE == 23) {
        if (bn >= 1024 && bn < 3072) {
            // ---- V panel transpose: coalesced vtg writes ----
            // Block output: s in [bm,bm+128) x dd_global in [0,128) for head hh.
            const int hh = (bn - 1024) >> 7;
            const int bb = bm >> 11;
            const int sbase = bm & 2047;
            short* T = (short*)As;                 // 128 x 34 shorts (8704 B <= 16 KB)
            bf16* vt = (bf16*)d1;
#pragma unroll
            for (int p = 0; p < 4; p++) {
                __syncthreads();                   // As free (last frag reads done / prev panel read)
                // write phase: only (wn,ni) with dd_global base in this panel
#pragma unroll
                for (int ni = 0; ni < 4; ni++) {
                    int ddg = wn + ni * 16;        // dd base for this acc column
                    if (ddg >= p * 32 && ddg < p * 32 + 32) {
                        int ddl = ddg - p * 32 + fr;
                        int nl = bn + wn + ni * 16 + fr - 1024;
#pragma unroll
                        for (int mi = 0; mi < 4; mi++)
#pragma unroll
                            for (int j = 0; j < 4; j++) {
                                int sl = wm + mi * 16 + cr + j;
                                T[sl * 34 + ddl] = f2bf_s(acc[mi][ni][j] + bias1[nl]);
                            }
                    }
                }
                __syncthreads();
                // read+write-out phase: all 256 threads, coalesced 256B rows
#pragma unroll
                for (int half = 0; half < 2; half++) {
                    int ddl = (tid >> 4) + half * 16;   // 0..31
                    int sc = tid & 15;                  // 16 chunks of 8 s
                    short tmp[8];
#pragma unroll
                    for (int i = 0; i < 8; i++)
                        tmp[i] = T[(sc * 8 + i) * 34 + ddl];
                    bf16* dst = vt + ((size_t)(bb * HEADS + hh) * HEAD_DIM + p * 32 + ddl) * SEQ + sbase + sc * 8;
                    *(uint4*)dst = *(uint4*)tmp;
                }
            }
            return;
        }
    }

#pragma unroll
    for (int mi = 0; mi < 4; mi++) {
#pragma unroll
        for (int j = 0; j < 4; j++) {
            int m = bm + wm + mi * 16 + cr + j;
            int bb = m >> 11;
            int s = m & 2047;

            if constexpr (FUSE == 4) {
#pragma unroll
                for (int ni = 0; ni < 4; ni++) {
                    int n = bn + wn + ni * 16 + fr;
                    ((float*)d0)[(size_t)m * N + n] = acc[mi][ni][j] + bias0[n];
                }
            } else if constexpr (FUSE == 1) {
                if (bn < 512) {
#pragma unroll
                    for (int ni = 0; ni < 4; ni++) {
                        int n = bn + wn + ni * 16 + fr;
                        ((bf16*)d0)[(size_t)m * 512 + n] = __float2bfloat16(acc[mi][ni][j] + bias0[n]);
                    }
                } else if (bn < 1024) {
#pragma unroll
                    for (int ni = 0; ni < 4; ni++) {
                        int n = bn + wn + ni * 16 + fr - 512;
                        ((bf16*)d1)[(size_t)m * 512 + n] = __float2bfloat16(acc[mi][ni][j] + bias1[n]);
                    }
                } else {
#pragma unroll
                    for (int ni = 0; ni < 2; ni++) {
                        int nl = bn + wn + ni * 16 + fr - 1024;
                        int hh = nl >> 6, dd = nl & 63;
                        float rot = acc[mi][ni][j] + bias2[nl];
                        float pas = acc[mi][ni + 2][j] + bias2[nl + 32];
                        float c = cosT[s * 32 + dd], sn = sinT[s * 32 + dd];
                        bf16* o = (bf16*)d2 + ((size_t)(bb * HEADS + hh) * SEQ + s) * HEAD_DIM + 64 + dd;
                        o[0]  = __float2bfloat16(rot * c - pas * sn);
                        o[32] = __float2bfloat16(rot * sn + pas * c);
                    }
                }
            } else {   // FUSE == 23, non-v segments
                if (bn < 1024) {
#pragma unroll
                    for (int ni = 0; ni < 4; ni++) {
                        int nl = bn + wn + ni * 16 + fr;
                        int hh = nl >> 6, dd = nl & 63;
                        ((bf16*)d0)[((size_t)(bb * HEADS + hh) * SEQ + s) * HEAD_DIM + dd] =
                            __float2bfloat16(acc[mi][ni][j] + bias0[nl]);
                    }
                } else if (bn < 4096) {
#pragma unroll
                    for (int ni = 0; ni < 4; ni++) {
                        int nl = bn + wn + ni * 16 + fr - 3072;
                        int hh = nl >> 6, dd = nl & 63;
                        ((bf16*)d2)[((size_t)(bb * HEADS + hh) * SEQ + s) * HEAD_DIM + dd] =
                            __float2bfloat16((acc[mi][ni][j] + bias2[nl]) * ATTN_SCALE);
                    }
                } else {
#pragma unroll
                    for (int ni = 0; ni < 2; ni++) {
                        int nl = bn + wn + ni * 16 + fr - 4096;
                        int hh = nl >> 6, dd = nl & 63;
                        float rot = (acc[mi][ni][j] + bias3[nl]) * ATTN_SCALE;
                        float pas = (acc[mi][ni + 2][j] + bias3[nl + 32]) * ATTN_SCALE;
                        float c = cosT[s * 32 + dd], sn = sinT[s * 32 + dd];
                        bf16* o = (bf16*)d2 + ((size_t)(bb * HEADS + hh) * SEQ + s) * HEAD_DIM + 64 + dd;
                        o[0]  = __float2bfloat16(rot * c - pas * sn);
                        o[32] = __float2bfloat16(rot * sn + pas * c);
                    }
                }
            }
        }
    }
}

// ---------------- MFMA causal flash attention (r15 + diag-split softmax) ----------------
__global__ __launch_bounds__(256) void attn_mfma_kernel(
    const bf16* __restrict__ qg, const bf16* __restrict__ kg,
    const bf16* __restrict__ vtg, bf16* __restrict__ outp)
{
    const int f = blockIdx.x;
    const int xcd = f & 7, slot = f >> 3;
    const int g = xcd * 4 + (slot >> 4);   // 0..31
    const int pid = slot & 15;
    const int b = g >> 4, h = g & 15;

    const int tid = threadIdx.x;
    const int w = tid >> 6, lane = tid & 63;
    const int fr = lane & 15, fq = lane >> 4;
    const int r7 = fr & 7;

    const bf16* Q  = qg  + (size_t)(b * HEADS + h) * SEQ * HEAD_DIM;
    const bf16* K  = kg  + (size_t)(b * HEADS + h) * SEQ * HEAD_DIM;
    const bf16* Vt = vtg + (size_t)(b * HEADS + h) * HEAD_DIM * SEQ;

    __shared__ __align__(16) short Ks[2][64 * 128];   // [key][d]
    __shared__ __align__(16) short Vs[2][128 * 64];   // [d][key]
    __shared__ __align__(16) short Ps[64 * 64];       // [q][key]

    const int krow = tid >> 4;
    const int kch  = tid & 15;
    const int vrow = tid >> 3;
    const int vch  = tid & 7;

#pragma unroll 1
    for (int seg = 0; seg < 2; seg++) {
        const int qt = seg ? (31 - pid) : pid;
        const int q0 = qt * 64;
        const int qrow = q0 + w * 16 + fr;

        bf16x8 qf[4];
#pragma unroll
        for (int kk = 0; kk < 4; kk++)
            qf[kk] = *(const bf16x8*)(Q + (size_t)(q0 + w * 16 + fr) * HEAD_DIM + kk * 32 + fq * 8);

        f32x4 accO[8];
#pragma unroll
        for (int ci = 0; ci < 8; ci++) accO[ci] = (f32x4){0.f, 0.f, 0.f, 0.f};
        float m_run = -INFINITY, l_run = 0.f;

        __syncthreads();
#pragma unroll
        for (int p = 0; p < 4; p++) {
            int rK = krow + p * 16;
            GLOAD_LDS(K + (size_t)rK * HEAD_DIM + ((kch ^ (rK & 7)) * 8), &Ks[0][rK * 128 + kch * 8]);
            int rV = vrow + p * 32;
            GLOAD_LDS(Vt + (size_t)rV * SEQ + ((vch ^ (rV & 7)) * 8), &Vs[0][rV * 64 + vch * 8]);
        }

        int cur = 0;
        for (int kt = 0; kt <= qt; kt++) {
            __syncthreads();
            if (kt < qt) {
#pragma unroll
                for (int p = 0; p < 4; p++) {
                    int rK = krow + p * 16;
                    GLOAD_LDS(K + (size_t)((kt + 1) * 64 + rK) * HEAD_DIM + ((kch ^ (rK & 7)) * 8),
                              &Ks[cur ^ 1][rK * 128 + kch * 8]);
                    int rV = vrow + p * 32;
                    GLOAD_LDS(Vt + (size_t)rV * SEQ + (kt + 1) * 64 + ((vch ^ (rV & 7)) * 8),
                              &Vs[cur ^ 1][rV * 64 + vch * 8]);
                }
            }

            f32x4 accS[4];
#pragma unroll
            for (int ni = 0; ni < 4; ni++) accS[ni] = (f32x4){0.f, 0.f, 0.f, 0.f};
#pragma unroll
            for (int kk = 0; kk < 4; kk++) {
#pragma unroll
                for (int ni = 0; ni < 4; ni++) {
                    bf16x8 kf = *(const bf16x8*)&Ks[cur][(ni * 16 + fr) * 128 + (((kk * 4 + fq) ^ r7) * 8)];
                    accS[ni] = __builtin_amdgcn_mfma_f32_16x16x32_bf16(kf, qf[kk], accS[ni], 0, 0, 0);
                }
            }

            // lane-local softmax (Q pre-scaled); diag-split masking
            float pv[16];
            float mloc = -INFINITY;
            if (kt == qt) {
#pragma unroll
                for (int ni = 0; ni < 4; ni++)
#pragma unroll
                    for (int reg = 0; reg < 4; reg++) {
                        float sc = accS[ni][reg];
                        int key = kt * 64 + ni * 16 + fq * 4 + reg;
                        if (key > qrow) sc = -INFINITY;
                        pv[ni * 4 + reg] = sc;
                        mloc = fmaxf(mloc, sc);
                    }
            } else {
#pragma unroll
                for (int ni = 0; ni < 4; ni++)
#pragma unroll
                    for (int reg = 0; reg < 4; reg++) {
                        float sc = accS[ni][reg];
                        pv[ni * 4 + reg] = sc;
                        mloc = fmaxf(mloc, sc);
                    }
            }
            mloc = fmaxf(mloc, __shfl_xor(mloc, 16));
            mloc = fmaxf(mloc, __shfl_xor(mloc, 32));
            float mn = fmaxf(m_run, mloc);
            float rs = __expf(m_run - mn);
            m_run = mn;
            float sum = 0.f;
#pragma unroll
            for (int i = 0; i < 16; i++) {
                float p = __expf(pv[i] - mn);
                pv[i] = p;
                sum += p;
            }
            sum += __shfl_xor(sum, 16);
            sum += __shfl_xor(sum, 32);
            l_run = l_run * rs + sum;

            if (__any(rs < 1.0f)) {
                float rsb[4];
#pragma unroll
                for (int reg = 0; reg < 4; reg++) rsb[reg] = __shfl(rs, fq * 4 + reg);
#pragma unroll
                for (int ci = 0; ci < 8; ci++)
#pragma unroll
                    for (int reg = 0; reg < 4; reg++)
                        accO[ci][reg] *= rsb[reg];
            }

#pragma unroll
            for (int ni = 0; ni < 4; ni++) {
                unsigned lo = (unsigned)(u16)f2bf_s(pv[ni * 4 + 0]) | ((unsigned)(u16)f2bf_s(pv[ni * 4 + 1]) << 16);
                unsigned hi = (unsigned)(u16)f2bf_s(pv[ni * 4 + 2]) | ((unsigned)(u16)f2bf_s(pv[ni * 4 + 3]) << 16);
                uint2 u; u.x = lo; u.y = hi;
                *(uint2*)&Ps[(w * 16 + fr) * 64 + (((2 * ni + (fq >> 1)) ^ r7) * 8) + (fq & 1) * 4] = u;
            }

#pragma unroll
            for (int kk = 0; kk < 2; kk++) {
                bf16x8 pf = *(const bf16x8*)&Ps[(w * 16 + fr) * 64 + (((kk * 4 + fq) ^ r7) * 8)];
#pragma unroll
                for (int ci = 0; ci < 8; ci++) {
                    bf16x8 vf = *(const bf16x8*)&Vs[cur][(ci * 16 + fr) * 64 + (((kk * 4 + fq) ^ r7) * 8)];
                    accO[ci] = __builtin_amdgcn_mfma_f32_16x16x32_bf16(pf, vf, accO[ci], 0, 0, 0);
                }
            }
            cur ^= 1;
        }

        float linv = 1.0f / l_run;
#pragma unroll
        for (int reg = 0; reg < 4; reg++) {
            float invb = __shfl(linv, fq * 4 + reg);
            bf16* dst = outp + ((size_t)(b * SEQ) + q0 + w * 16 + fq * 4 + reg) * HIDDEN + h * HEAD_DIM + fr;
#pragma unroll
            for (int ci = 0; ci < 8; ci++)
                dst[ci * 16] = __float2bfloat16(accO[ci][reg] * invb);
        }
    }
}

extern "C" void kernel_launch(void* const* d_in, const int* in_sizes, int n_in,
                              void* d_out, int out_size, void* d_ws, size_t ws_size,
                              hipStream_t stream)
{
    const float* x      = (const float*)d_in[0];
    // d_in[1] = attention_mask (int32 causal tril) — causality implemented directly
    const float* W_kv_d = (const float*)d_in[2];
    const float* b_kv_d = (const float*)d_in[3];
    const float* W_q_d  = (const float*)d_in[4];
    const float* b_q_d  = (const float*)d_in[5];
    const float* W_k_u  = (const float*)d_in[6];
    const float* b_k_u  = (const float*)d_in[7];
    const float* W_q_u  = (const float*)d_in[8];
    const float* b_q_u  = (const float*)d_in[9];
    const float* W_v_u  = (const float*)d_in[10];
    const float* b_v_u  = (const float*)d_in[11];
    const float* W_rk   = (const float*)d_in[12];
    const float* b_rk   = (const float*)d_in[13];
    const float* W_rq   = (const float*)d_in[14];
    const float* b_rq   = (const float*)d_in[15];
    const float* W_o    = (const float*)d_in[16];
    const float* b_o    = (const float*)d_in[17];

    // ---- workspace layout (~112 MB) ----
    float* cosT = (float*)d_ws;
    float* sinT = cosT + SEQ * 32;
    bf16* kv_d  = (bf16*)(sinT + SEQ * 32);
    bf16* q_d   = kv_d + (size_t)MROWS * LATENT;
    bf16* qg    = q_d + (size_t)MROWS * LATENT;
    bf16* kg    = qg + (size_t)BATCH * HEADS * SEQ * HEAD_DIM;
    bf16* vtg   = kg + (size_t)BATCH * HEADS * SEQ * HEAD_DIM;
    bf16* attnb = vtg + (size_t)BATCH * HEADS * SEQ * HEAD_DIM;
    bf16* xb    = attnb + (size_t)MROWS * HIDDEN;
    bf16* Wt_g1 = xb + (size_t)MROWS * HIDDEN;
    bf16* Wt_g2 = Wt_g1 + (size_t)2048 * HIDDEN;
    bf16* Wt_o  = Wt_g2 + (size_t)5120 * LATENT;

    prep_kernel<<<15104, 256, 0, stream>>>(
        x, xb, W_kv_d, W_q_d, W_rk, W_k_u, W_v_u, W_q_u, W_rq, W_o,
        Wt_g1, Wt_g2, Wt_o, cosT, sinT);

    mfma_gemm<1><<<dim3(2048 / 128, MROWS / 128), 256, 0, stream>>>(
        xb, nullptr, Wt_g1, b_kv_d, b_q_d, b_rk, nullptr, kv_d, q_d, kg, cosT, sinT, MROWS, 2048, HIDDEN);

    mfma_gemm<23><<<dim3(5120 / 128, MROWS / 128), 256, 0, stream>>>(
        kv_d, q_d, Wt_g2, b_k_u, b_v_u, b_q_u, b_rq, kg, vtg, qg, cosT, sinT, MROWS, 5120, LATENT);

    attn_mfma_kernel<<<512, 256, 0, stream>>>(qg, kg, vtg, attnb);

    mfma_gemm<4><<<dim3(2048 / 128, MROWS / 128), 256, 0, stream>>>(
        attnb, nullptr, Wt_o, b_o, nullptr, nullptr, nullptr, d_out, nullptr, nullptr, nullptr, nullptr, MROWS, 2048, HIDDEN);
}

// Round 17
// 241.193 us; speedup vs baseline: 6.3487x; 1.0008x over previous
//
#include <hip/hip_runtime.h>
#include <hip/hip_bf16.h>
#include <math.h>

#define HIDDEN 2048
#define HEADS 16
#define HEAD_DIM 128
#define LATENT 512
#define SEQ 2048
#define BATCH 2
#define MROWS (BATCH*SEQ)
#define ATTN_SCALE 0.08838834764831845f  // 1/sqrt(128)

typedef unsigned short u16;
typedef __hip_bfloat16 bf16;
typedef __attribute__((ext_vector_type(8))) short bf16x8;
typedef __attribute__((ext_vector_type(4))) float f32x4;

__device__ inline float bf2f(u16 u) { return __uint_as_float(((unsigned)u) << 16); }
__device__ inline short f2bf_s(float v) { bf16 t = __float2bfloat16(v); return *(short*)&t; }

#define GLOAD_LDS(gp, lp) \
    __builtin_amdgcn_global_load_lds((const __attribute__((address_space(1))) unsigned int*)(gp), \
                                     (__attribute__((address_space(3))) unsigned int*)(lp), 16, 0, 0)

// ---------------- mega-prep: rope tables + x cast + all weight transpose-casts ----------------
__global__ __launch_bounds__(256) void prep_kernel(
    const float* __restrict__ x, bf16* __restrict__ xb,
    const float* __restrict__ W_kv_d, const float* __restrict__ W_q_d, const float* __restrict__ W_rk,
    const float* __restrict__ W_k_u, const float* __restrict__ W_v_u,
    const float* __restrict__ W_q_u, const float* __restrict__ W_rq, const float* __restrict__ W_o,
    bf16* __restrict__ Wt_g1, bf16* __restrict__ Wt_g2, bf16* __restrict__ Wt_o,
    float* __restrict__ cosT, float* __restrict__ sinT)
{
    const int tid = threadIdx.x;
    int r = blockIdx.x;

    if (r < 256) {   // rope tables
        int gid = r * 256 + tid;
        int t = gid >> 5, j = gid & 31;
        float inv = powf(10000.0f, -(float)j * (1.0f / 32.0f));
        float ang = (float)t * inv;
        cosT[gid] = cosf(ang);
        sinT[gid] = sinf(ang);
        return;
    }
    r -= 256;
    if (r < 4096) {  // castx
        size_t gid = (size_t)r * 256 + tid;
        const float* p = x + gid * 8;
        float4 a = *(const float4*)p;
        float4 b = *(const float4*)(p + 4);
        bf16 o[8] = {__float2bfloat16(a.x), __float2bfloat16(a.y), __float2bfloat16(a.z), __float2bfloat16(a.w),
                     __float2bfloat16(b.x), __float2bfloat16(b.y), __float2bfloat16(b.z), __float2bfloat16(b.w)};
        *(uint4*)(xb + gid * 8) = *(uint4*)o;
        return;
    }
    r -= 4096;

    // tcast segment select: W (K,N) fp32 -> Wt (N,K) bf16
    const float* W; bf16* Wt; int K, N;
    if (r < 1024)            { W = W_kv_d; Wt = Wt_g1;                        K = 2048; N = 512;  }
    else if (r < 2048)       { r -= 1024; W = W_q_d; Wt = Wt_g1 + (size_t)512 * 2048;  K = 2048; N = 512;  }
    else if (r < 4096)       { r -= 2048; W = W_rk;  Wt = Wt_g1 + (size_t)1024 * 2048; K = 2048; N = 1024; }
    else if (r < 4608)       { r -= 4096; W = W_k_u; Wt = Wt_g2;                       K = 512;  N = 1024; }
    else if (r < 5632)       { r -= 4608; W = W_v_u; Wt = Wt_g2 + (size_t)1024 * 512;  K = 512;  N = 2048; }
    else if (r < 6144)       { r -= 5632; W = W_q_u; Wt = Wt_g2 + (size_t)3072 * 512;  K = 512;  N = 1024; }
    else if (r < 6656)       { r -= 6144; W = W_rq;  Wt = Wt_g2 + (size_t)4096 * 512;  K = 512;  N = 1024; }
    else                     { r -= 6656; W = W_o;   Wt = Wt_o;                        K = 2048; N = 2048; }

    const int kb = r % (K / 32), nb = r / (K / 32);
    const int k0 = kb * 32, n0 = nb * 32;
    __shared__ float T[32][33];
    const int tx = tid & 31, ty = tid >> 5;
#pragma unroll
    for (int p = 0; p < 4; p++) {
        int kr = p * 8 + ty;
        T[kr][tx] = W[(size_t)(k0 + kr) * N + n0 + tx];
    }
    __syncthreads();
#pragma unroll
    for (int p = 0; p < 4; p++) {
        int nr = p * 8 + ty;
        Wt[(size_t)(n0 + nr) * K + k0 + tx] = __float2bfloat16(T[tx][nr]);
    }
}

// ---------------- fused MFMA GEMM ----------------
// FUSE 1:  [0,512) plain->d0(kv_d); [512,1024) plain->d1(q_d); [1024,2048) rope-scatter->d2(kg hi)
// FUSE 23: N=5120, K=512. A = (bn<3072 ? A : A2).
//          [0,1024) k1->d0(kg lo); [1024,3072) v-transpose via LDS panels->d1(vtg);
//          [3072,4096) q1*SCALE->d2(qg lo); [4096,5120) rope(q2)*SCALE->d2(qg hi)
// FUSE 4:  fp32 plain->d0
template<int FUSE>
__global__ __launch_bounds__(256) void mfma_gemm(
    const bf16* __restrict__ A, const bf16* __restrict__ A2, const bf16* __restrict__ Bt,
    const float* __restrict__ bias0, const float* __restrict__ bias1,
    const float* __restrict__ bias2, const float* __restrict__ bias3,
    void* __restrict__ d0, void* __restrict__ d1, void* __restrict__ d2,
    const float* __restrict__ cosT, const float* __restrict__ sinT,
    int M, int N, int K)
{
    constexpr int BM = 128, BN = 128, BK = 32;
    __shared__ __align__(16) short As[2][BM * BK];
    __shared__ __align__(16) short Bs[2][BN * BK];

    const int tid = threadIdx.x;
    const int wid = tid >> 6;
    const int lane = tid & 63;
    const int wm = (wid >> 1) * 64;
    const int wn = (wid & 1) * 64;
    const int bm = blockIdx.y * BM, bn = blockIdx.x * BN;
    const int fr = lane & 15;
    const int fk = lane >> 4;

    const int srowA = wid * 32 + (lane >> 2);
    const int scol = (lane & 3) * 8;

    const bf16* Abase = A;
    if constexpr (FUSE == 23) { if (bn >= 3072) Abase = A2; }

    f32x4 acc[4][4];
#pragma unroll
    for (int mi = 0; mi < 4; mi++)
#pragma unroll
        for (int ni = 0; ni < 4; ni++)
            acc[mi][ni] = (f32x4){0.f, 0.f, 0.f, 0.f};

    const int NT = K / BK;
#pragma unroll
    for (int i = 0; i < 2; i++) {
        GLOAD_LDS(Abase + (size_t)(bm + srowA + i * 16) * K + scol, &As[0][(wid * 32 + i * 16) * BK]);
        GLOAD_LDS(Bt + (size_t)(bn + srowA + i * 16) * K + scol, &Bs[0][(wid * 32 + i * 16) * BK]);
    }

    int cur = 0;
    for (int t = 0; t < NT; t++) {
        __syncthreads();
        if (t + 1 < NT) {
            size_t kk = (size_t)(t + 1) * BK;
#pragma unroll
            for (int i = 0; i < 2; i++) {
                GLOAD_LDS(Abase + (size_t)(bm + srowA + i * 16) * K + kk + scol, &As[cur ^ 1][(wid * 32 + i * 16) * BK]);
                GLOAD_LDS(Bt + (size_t)(bn + srowA + i * 16) * K + kk + scol, &Bs[cur ^ 1][(wid * 32 + i * 16) * BK]);
            }
        }
        bf16x8 af[4], bfr[4];
#pragma unroll
        for (int mi = 0; mi < 4; mi++)
            af[mi] = *(const bf16x8*)&As[cur][(wm + mi * 16 + fr) * BK + fk * 8];
#pragma unroll
        for (int ni = 0; ni < 4; ni++)
            bfr[ni] = *(const bf16x8*)&Bs[cur][(wn + ni * 16 + fr) * BK + fk * 8];
#pragma unroll
        for (int mi = 0; mi < 4; mi++)
#pragma unroll
            for (int ni = 0; ni < 4; ni++)
                acc[mi][ni] = __builtin_amdgcn_mfma_f32_16x16x32_bf16(af[mi], bfr[ni], acc[mi][ni], 0, 0, 0);
        cur ^= 1;
    }

    const int cr = (lane >> 4) * 4;

    if constexpr (FUSE == 23) {
        if (bn >= 1024 && bn < 3072) {
            // ---- V panel transpose: coalesced vtg writes ----
            const int hh = (bn - 1024) >> 7;
            const int bb = bm >> 11;
            const int sbase = bm & 2047;
            short* T = (short*)As;                 // 128 x 34 shorts
            bf16* vt = (bf16*)d1;
#pragma unroll
            for (int p = 0; p < 4; p++) {
                __syncthreads();
#pragma unroll
                for (int ni = 0; ni < 4; ni++) {
                    int ddg = wn + ni * 16;
                    if (ddg >= p * 32 && ddg < p * 32 + 32) {
                        int ddl = ddg - p * 32 + fr;
                        int nl = bn + wn + ni * 16 + fr - 1024;
#pragma unroll
                        for (int mi = 0; mi < 4; mi++)
#pragma unroll
                            for (int j = 0; j < 4; j++) {
                                int sl = wm + mi * 16 + cr + j;
                                T[sl * 34 + ddl] = f2bf_s(acc[mi][ni][j] + bias1[nl]);
                            }
                    }
                }
                __syncthreads();
#pragma unroll
                for (int half = 0; half < 2; half++) {
                    int ddl = (tid >> 4) + half * 16;
                    int sc = tid & 15;
                    short tmp[8];
#pragma unroll
                    for (int i = 0; i < 8; i++)
                        tmp[i] = T[(sc * 8 + i) * 34 + ddl];
                    bf16* dst = vt + ((size_t)(bb * HEADS + hh) * HEAD_DIM + p * 32 + ddl) * SEQ + sbase + sc * 8;
                    *(uint4*)dst = *(uint4*)tmp;
                }
            }
            return;
        }
    }

#pragma unroll
    for (int mi = 0; mi < 4; mi++) {
#pragma unroll
        for (int j = 0; j < 4; j++) {
            int m = bm + wm + mi * 16 + cr + j;
            int bb = m >> 11;
            int s = m & 2047;

            if constexpr (FUSE == 4) {
#pragma unroll
                for (int ni = 0; ni < 4; ni++) {
                    int n = bn + wn + ni * 16 + fr;
                    ((float*)d0)[(size_t)m * N + n] = acc[mi][ni][j] + bias0[n];
                }
            } else if constexpr (FUSE == 1) {
                if (bn < 512) {
#pragma unroll
                    for (int ni = 0; ni < 4; ni++) {
                        int n = bn + wn + ni * 16 + fr;
                        ((bf16*)d0)[(size_t)m * 512 + n] = __float2bfloat16(acc[mi][ni][j] + bias0[n]);
                    }
                } else if (bn < 1024) {
#pragma unroll
                    for (int ni = 0; ni < 4; ni++) {
                        int n = bn + wn + ni * 16 + fr - 512;
                        ((bf16*)d1)[(size_t)m * 512 + n] = __float2bfloat16(acc[mi][ni][j] + bias1[n]);
                    }
                } else {
#pragma unroll
                    for (int ni = 0; ni < 2; ni++) {
                        int nl = bn + wn + ni * 16 + fr - 1024;
                        int hh = nl >> 6, dd = nl & 63;
                        float rot = acc[mi][ni][j] + bias2[nl];
                        float pas = acc[mi][ni + 2][j] + bias2[nl + 32];
                        float c = cosT[s * 32 + dd], sn = sinT[s * 32 + dd];
                        bf16* o = (bf16*)d2 + ((size_t)(bb * HEADS + hh) * SEQ + s) * HEAD_DIM + 64 + dd;
                        o[0]  = __float2bfloat16(rot * c - pas * sn);
                        o[32] = __float2bfloat16(rot * sn + pas * c);
                    }
                }
            } else {   // FUSE == 23, non-v segments
                if (bn < 1024) {
#pragma unroll
                    for (int ni = 0; ni < 4; ni++) {
                        int nl = bn + wn + ni * 16 + fr;
                        int hh = nl >> 6, dd = nl & 63;
                        ((bf16*)d0)[((size_t)(bb * HEADS + hh) * SEQ + s) * HEAD_DIM + dd] =
                            __float2bfloat16(acc[mi][ni][j] + bias0[nl]);
                    }
                } else if (bn < 4096) {
#pragma unroll
                    for (int ni = 0; ni < 4; ni++) {
                        int nl = bn + wn + ni * 16 + fr - 3072;
                        int hh = nl >> 6, dd = nl & 63;
                        ((bf16*)d2)[((size_t)(bb * HEADS + hh) * SEQ + s) * HEAD_DIM + dd] =
                            __float2bfloat16((acc[mi][ni][j] + bias2[nl]) * ATTN_SCALE);
                    }
                } else {
#pragma unroll
                    for (int ni = 0; ni < 2; ni++) {
                        int nl = bn + wn + ni * 16 + fr - 4096;
                        int hh = nl >> 6, dd = nl & 63;
                        float rot = (acc[mi][ni][j] + bias3[nl]) * ATTN_SCALE;
                        float pas = (acc[mi][ni + 2][j] + bias3[nl + 32]) * ATTN_SCALE;
                        float c = cosT[s * 32 + dd], sn = sinT[s * 32 + dd];
                        bf16* o = (bf16*)d2 + ((size_t)(bb * HEADS + hh) * SEQ + s) * HEAD_DIM + 64 + dd;
                        o[0]  = __float2bfloat16(rot * c - pas * sn);
                        o[32] = __float2bfloat16(rot * sn + pas * c);
                    }
                }
            }
        }
    }
}

// ---------------- MFMA causal flash attention (r16 + setprio + cross-segment prefetch) ----------------
__global__ __launch_bounds__(256) void attn_mfma_kernel(
    const bf16* __restrict__ qg, const bf16* __restrict__ kg,
    const bf16* __restrict__ vtg, bf16* __restrict__ outp)
{
    const int f = blockIdx.x;
    const int xcd = f & 7, slot = f >> 3;
    const int g = xcd * 4 + (slot >> 4);   // 0..31
    const int pid = slot & 15;
    const int b = g >> 4, h = g & 15;

    const int tid = threadIdx.x;
    const int w = tid >> 6, lane = tid & 63;
    const int fr = lane & 15, fq = lane >> 4;
    const int r7 = fr & 7;

    const bf16* Q  = qg  + (size_t)(b * HEADS + h) * SEQ * HEAD_DIM;
    const bf16* K  = kg  + (size_t)(b * HEADS + h) * SEQ * HEAD_DIM;
    const bf16* Vt = vtg + (size_t)(b * HEADS + h) * HEAD_DIM * SEQ;

    __shared__ __align__(16) short Ks[2][64 * 128];   // [key][d]
    __shared__ __align__(16) short Vs[2][128 * 64];   // [d][key]
    __shared__ __align__(16) short Ps[64 * 64];       // [q][key]

    const int krow = tid >> 4;
    const int kch  = tid & 15;
    const int vrow = tid >> 3;
    const int vch  = tid & 7;

    int cur = 0;
    // prologue: stage seg-0 tile 0 -> buf 0 (async)
#pragma unroll
    for (int p = 0; p < 4; p++) {
        int rK = krow + p * 16;
        GLOAD_LDS(K + (size_t)rK * HEAD_DIM + ((kch ^ (rK & 7)) * 8), &Ks[0][rK * 128 + kch * 8]);
        int rV = vrow + p * 32;
        GLOAD_LDS(Vt + (size_t)rV * SEQ + ((vch ^ (rV & 7)) * 8), &Vs[0][rV * 64 + vch * 8]);
    }

#pragma unroll 1
    for (int seg = 0; seg < 2; seg++) {
        const int qt = seg ? (31 - pid) : pid;
        const int q0 = qt * 64;
        const int qrow = q0 + w * 16 + fr;

        bf16x8 qf[4];
#pragma unroll
        for (int kk = 0; kk < 4; kk++)
            qf[kk] = *(const bf16x8*)(Q + (size_t)(q0 + w * 16 + fr) * HEAD_DIM + kk * 32 + fq * 8);

        f32x4 accO[8];
#pragma unroll
        for (int ci = 0; ci < 8; ci++) accO[ci] = (f32x4){0.f, 0.f, 0.f, 0.f};
        float m_run = -INFINITY, l_run = 0.f;

        for (int kt = 0; kt <= qt; kt++) {
            __syncthreads();   // drains vmcnt: buf[cur] ready; prior reads of buf[cur^1] done
            if (kt < qt) {     // async prefetch of next tile
#pragma unroll
                for (int p = 0; p < 4; p++) {
                    int rK = krow + p * 16;
                    GLOAD_LDS(K + (size_t)((kt + 1) * 64 + rK) * HEAD_DIM + ((kch ^ (rK & 7)) * 8),
                              &Ks[cur ^ 1][rK * 128 + kch * 8]);
                    int rV = vrow + p * 32;
                    GLOAD_LDS(Vt + (size_t)rV * SEQ + (kt + 1) * 64 + ((vch ^ (rV & 7)) * 8),
                              &Vs[cur ^ 1][rV * 64 + vch * 8]);
                }
            } else if (seg == 0) {
                // cross-segment prefetch: stage seg-1 tile 0 during seg-0's last tile
#pragma unroll
                for (int p = 0; p < 4; p++) {
                    int rK = krow + p * 16;
                    GLOAD_LDS(K + (size_t)rK * HEAD_DIM + ((kch ^ (rK & 7)) * 8),
                              &Ks[cur ^ 1][rK * 128 + kch * 8]);
                    int rV = vrow + p * 32;
                    GLOAD_LDS(Vt + (size_t)rV * SEQ + ((vch ^ (rV & 7)) * 8),
                              &Vs[cur ^ 1][rV * 64 + vch * 8]);
                }
            }

            // QK^T swapped: A=K(rows=key), B=Q(rows=q). C: col=fr=q, row=fq*4+reg=key_sub
            f32x4 accS[4];
#pragma unroll
            for (int ni = 0; ni < 4; ni++) accS[ni] = (f32x4){0.f, 0.f, 0.f, 0.f};
            __builtin_amdgcn_s_setprio(1);
#pragma unroll
            for (int kk = 0; kk < 4; kk++) {
#pragma unroll
                for (int ni = 0; ni < 4; ni++) {
                    bf16x8 kf = *(const bf16x8*)&Ks[cur][(ni * 16 + fr) * 128 + (((kk * 4 + fq) ^ r7) * 8)];
                    accS[ni] = __builtin_amdgcn_mfma_f32_16x16x32_bf16(kf, qf[kk], accS[ni], 0, 0, 0);
                }
            }
            __builtin_amdgcn_s_setprio(0);

            // lane-local softmax (Q pre-scaled); diag-split masking
            float pv[16];
            float mloc = -INFINITY;
            if (kt == qt) {
#pragma unroll
                for (int ni = 0; ni < 4; ni++)
#pragma unroll
                    for (int reg = 0; reg < 4; reg++) {
                        float sc = accS[ni][reg];
                        int key = kt * 64 + ni * 16 + fq * 4 + reg;
                        if (key > qrow) sc = -INFINITY;
                        pv[ni * 4 + reg] = sc;
                        mloc = fmaxf(mloc, sc);
                    }
            } else {
#pragma unroll
                for (int ni = 0; ni < 4; ni++)
#pragma unroll
                    for (int reg = 0; reg < 4; reg++) {
                        float sc = accS[ni][reg];
                        pv[ni * 4 + reg] = sc;
                        mloc = fmaxf(mloc, sc);
                    }
            }
            mloc = fmaxf(mloc, __shfl_xor(mloc, 16));
            mloc = fmaxf(mloc, __shfl_xor(mloc, 32));
            float mn = fmaxf(m_run, mloc);
            float rs = __expf(m_run - mn);
            m_run = mn;
            float sum = 0.f;
#pragma unroll
            for (int i = 0; i < 16; i++) {
                float p = __expf(pv[i] - mn);
                pv[i] = p;
                sum += p;
            }
            sum += __shfl_xor(sum, 16);
            sum += __shfl_xor(sum, 32);
            l_run = l_run * rs + sum;

            if (__any(rs < 1.0f)) {
                float rsb[4];
#pragma unroll
                for (int reg = 0; reg < 4; reg++) rsb[reg] = __shfl(rs, fq * 4 + reg);
#pragma unroll
                for (int ci = 0; ci < 8; ci++)
#pragma unroll
                    for (int reg = 0; reg < 4; reg++)
                        accO[ci][reg] *= rsb[reg];
            }

#pragma unroll
            for (int ni = 0; ni < 4; ni++) {
                unsigned lo = (unsigned)(u16)f2bf_s(pv[ni * 4 + 0]) | ((unsigned)(u16)f2bf_s(pv[ni * 4 + 1]) << 16);
                unsigned hi = (unsigned)(u16)f2bf_s(pv[ni * 4 + 2]) | ((unsigned)(u16)f2bf_s(pv[ni * 4 + 3]) << 16);
                uint2 u; u.x = lo; u.y = hi;
                *(uint2*)&Ps[(w * 16 + fr) * 64 + (((2 * ni + (fq >> 1)) ^ r7) * 8) + (fq & 1) * 4] = u;
            }

            __builtin_amdgcn_s_setprio(1);
#pragma unroll
            for (int kk = 0; kk < 2; kk++) {
                bf16x8 pf = *(const bf16x8*)&Ps[(w * 16 + fr) * 64 + (((kk * 4 + fq) ^ r7) * 8)];
#pragma unroll
                for (int ci = 0; ci < 8; ci++) {
                    bf16x8 vf = *(const bf16x8*)&Vs[cur][(ci * 16 + fr) * 64 + (((kk * 4 + fq) ^ r7) * 8)];
                    accO[ci] = __builtin_amdgcn_mfma_f32_16x16x32_bf16(pf, vf, accO[ci], 0, 0, 0);
                }
            }
            __builtin_amdgcn_s_setprio(0);
            cur ^= 1;
        }

        float linv = 1.0f / l_run;
#pragma unroll
        for (int reg = 0; reg < 4; reg++) {
            float invb = __shfl(linv, fq * 4 + reg);
            bf16* dst = outp + ((size_t)(b * SEQ) + q0 + w * 16 + fq * 4 + reg) * HIDDEN + h * HEAD_DIM + fr;
#pragma unroll
            for (int ci = 0; ci < 8; ci++)
                dst[ci * 16] = __float2bfloat16(accO[ci][reg] * invb);
        }
    }
}

extern "C" void kernel_launch(void* const* d_in, const int* in_sizes, int n_in,
                              void* d_out, int out_size, void* d_ws, size_t ws_size,
                              hipStream_t stream)
{
    const float* x      = (const float*)d_in[0];
    // d_in[1] = attention_mask (int32 causal tril) — causality implemented directly
    const float* W_kv_d = (const float*)d_in[2];
    const float* b_kv_d = (const float*)d_in[3];
    const float* W_q_d  = (const float*)d_in[4];
    const float* b_q_d  = (const float*)d_in[5];
    const float* W_k_u  = (const float*)d_in[6];
    const float* b_k_u  = (const float*)d_in[7];
    const float* W_q_u  = (const float*)d_in[8];
    const float* b_q_u  = (const float*)d_in[9];
    const float* W_v_u  = (const float*)d_in[10];
    const float* b_v_u  = (const float*)d_in[11];
    const float* W_rk   = (const float*)d_in[12];
    const float* b_rk   = (const float*)d_in[13];
    const float* W_rq   = (const float*)d_in[14];
    const float* b_rq   = (const float*)d_in[15];
    const float* W_o    = (const float*)d_in[16];
    const float* b_o    = (const float*)d_in[17];

    // ---- workspace layout (~112 MB) ----
    float* cosT = (float*)d_ws;
    float* sinT = cosT + SEQ * 32;
    bf16* kv_d  = (bf16*)(sinT + SEQ * 32);
    bf16* q_d   = kv_d + (size_t)MROWS * LATENT;
    bf16* qg    = q_d + (size_t)MROWS * LATENT;
    bf16* kg    = qg + (size_t)BATCH * HEADS * SEQ * HEAD_DIM;
    bf16* vtg   = kg + (size_t)BATCH * HEADS * SEQ * HEAD_DIM;
    bf16* attnb = vtg + (size_t)BATCH * HEADS * SEQ * HEAD_DIM;
    bf16* xb    = attnb + (size_t)MROWS * HIDDEN;
    bf16* Wt_g1 = xb + (size_t)MROWS * HIDDEN;
    bf16* Wt_g2 = Wt_g1 + (size_t)2048 * HIDDEN;
    bf16* Wt_o  = Wt_g2 + (size_t)5120 * LATENT;

    prep_kernel<<<15104, 256, 0, stream>>>(
        x, xb, W_kv_d, W_q_d, W_rk, W_k_u, W_v_u, W_q_u, W_rq, W_o,
        Wt_g1, Wt_g2, Wt_o, cosT, sinT);

    mfma_gemm<1><<<dim3(2048 / 128, MROWS / 128), 256, 0, stream>>>(
        xb, nullptr, Wt_g1, b_kv_d, b_q_d, b_rk, nullptr, kv_d, q_d, kg, cosT, sinT, MROWS, 2048, HIDDEN);

    mfma_gemm<23><<<dim3(5120 / 128, MROWS / 128), 256, 0, stream>>>(
        kv_d, q_d, Wt_g2, b_k_u, b_v_u, b_q_u, b_rq, kg, vtg, qg, cosT, sinT, MROWS, 5120, LATENT);

    attn_mfma_kernel<<<512, 256, 0, stream>>>(qg, kg, vtg, attnb);

    mfma_gemm<4><<<dim3(2048 / 128, MROWS / 128), 256, 0, stream>>>(
        attnb, nullptr, Wt_o, b_o, nullptr, nullptr, nullptr, d_out, nullptr, nullptr, nullptr, nullptr, MROWS, 2048, HIDDEN);
}